// Round 4
// baseline (750.502 us; speedup 1.0000x reference)
//
#include <hip/hip_runtime.h>
#include <hip/hip_bf16.h>

// StARformer round 7: fused_mlp round-6 concept was right (FETCH matched
// prediction) but the compiler spilled the staging registers at its default
// 116-VGPR budget -> 566 MB of scratch writes. Fix: __launch_bounds__(256,2)
// to give the allocator a 256-VGPR budget (2 blocks/CU unchanged, LDS-bound).
// Everything else identical to round 6.

typedef unsigned short ushort;
typedef __bf16 bf16x8 __attribute__((ext_vector_type(8)));
typedef float f32x4 __attribute__((ext_vector_type(4)));

__device__ __forceinline__ ushort f2us(float f) {
  __hip_bfloat16 h = __float2bfloat16(f);
  return *reinterpret_cast<ushort*>(&h);
}
__device__ __forceinline__ float gelu_exact(float v) {
  return 0.5f * v * (1.f + erff(v * 0.70710678118654752f));
}
__device__ __forceinline__ void gload16(const ushort* g, ushort* l) {
  __builtin_amdgcn_global_load_lds(
      (const __attribute__((address_space(1))) void*)g,
      (__attribute__((address_space(3))) void*)l, 16, 0, 0);
}

// ---------- batched transpose+convert: 13 weight jobs in one launch ----------
struct TJobs { const float* s[13]; ushort* d[13]; };

__global__ __launch_bounds__(256)
void transp_all(TJobs J)
{
  static constexpr int NN[13]  = {192,192,192,192,768,192,768,768,768,768,768,3072,768};
  static constexpr int SS[13]  = {192,192,192,192,192,768,12288,768,768,768,768,768,3072};
  static constexpr int RO[13]  = {0,192,384,0,0,0,0,0,768,1536,0,0,0};
  static constexpr int CUM[14] = {0,9,18,27,36,72,108,2412,2556,2700,2844,2988,3564,4140};
  __shared__ float t[64][65];
  int bid = blockIdx.x;
  int j = 0;
  while (bid >= CUM[j + 1]) ++j;
  int tIdx = bid - CUM[j];
  const int N = NN[j], stride = SS[j], rowOff = RO[j];
  const int nx = N >> 6;
  const int n0 = (tIdx % nx) * 64, k0 = (tIdx / nx) * 64;
  const float* W = J.s[j];
  ushort* Wt = J.d[j];
  int c = threadIdx.x & 63, r = threadIdx.x >> 6;
  #pragma unroll
  for (int i = 0; i < 16; ++i) {
    int kr = r + i * 4;
    t[kr][c] = W[(size_t)(k0 + kr) * N + n0 + c];
  }
  __syncthreads();
  #pragma unroll
  for (int i = 0; i < 16; ++i) {
    int nr = r + i * 4;
    Wt[(size_t)(rowOff + n0 + nr) * stride + k0 + c] = f2us(t[c][nr]);
  }
}

// ---------- pack 3 bias vectors ----------
__global__ __launch_bounds__(256)
void pack3_kernel(float* dst, const float* a, int na, const float* b, int nb,
                  const float* c, int nc)
{
  int i = blockIdx.x * 256 + threadIdx.x;
  if (i >= na + nb + nc) return;
  dst[i] = (i < na) ? a[i] : (i < na + nb ? b[i - na] : c[i - na - nb]);
}

// ---------- LayerNorm: one wave per row, fp32 in, bf16 out ----------
template<int D>
__global__ __launch_bounds__(256)
void ln_kernel(const float* __restrict__ x, const float* __restrict__ g,
               const float* __restrict__ bb, ushort* __restrict__ out, int rows)
{
  int wave = threadIdx.x >> 6, lane = threadIdx.x & 63;
  int row = blockIdx.x * 4 + wave;
  if (row >= rows) return;
  const float* xr = x + (size_t)row * D;
  constexpr int E = D / 64;
  float vals[E];
  float s = 0.f;
  #pragma unroll
  for (int e = 0; e < E; ++e) { vals[e] = xr[e * 64 + lane]; s += vals[e]; }
  #pragma unroll
  for (int off = 32; off >= 1; off >>= 1) s += __shfl_xor(s, off);
  float m = s * (1.f / D);
  float s2 = 0.f;
  #pragma unroll
  for (int e = 0; e < E; ++e) { float d = vals[e] - m; s2 += d * d; }
  #pragma unroll
  for (int off = 32; off >= 1; off >>= 1) s2 += __shfl_xor(s2, off);
  float rstd = rsqrtf(s2 * (1.f / D) + 1e-5f);
  ushort* orow = out + (size_t)row * D;
  #pragma unroll
  for (int e = 0; e < E; ++e) {
    int c = e * 64 + lane;
    orow[c] = f2us((vals[e] - m) * rstd * g[c] + bb[c]);
  }
}

// ---------- fused local MLP: out = res + b2 + gelu(A@w1 + b1) @ w2 ----------
// A: LN2 output [M][192] bf16. Per block: 64 rows. A fragments in registers.
// Loop 12 hid-tiles of 64: phase1 hid=A@w1t (gelu+b1 -> LDS), phase2 acc+=hid@w2t.
// __launch_bounds__(256,2): 256-VGPR budget -> no spill (r6 lesson: default
// budget was 116 VGPR and spilled 48 staging regs -> 566 MB scratch writes).
__global__ __launch_bounds__(256, 2)
void fused_mlp(const ushort* __restrict__ A, const ushort* __restrict__ W1t,
               const ushort* __restrict__ W2t, const float* __restrict__ b1,
               const float* __restrict__ b2, const float* __restrict__ resF,
               float* __restrict__ Cf, ushort* __restrict__ Cb)
{
  __shared__ __align__(16) ushort W1B[64 * 200];   // w1 tile [64 n][192 k], pad 200
  __shared__ __align__(16) ushort W2B[192 * 72];   // w2 tile [192 n][64 k], pad 72
  __shared__ __align__(16) ushort Hs[64 * 72];     // hid tile [64 r][64 k], pad 72
  const int tid = threadIdx.x;
  const int wave = tid >> 6, lane = tid & 63;
  const int quad = lane >> 4, lm = lane & 15;
  const int rowBase = blockIdx.x * 64;
  const int wr  = (wave & 1) * 32;     // row base (both phases)
  const int wc1 = (wave >> 1) * 32;    // phase1 hid-col base
  const int wc2 = (wave >> 1) * 96;    // phase2 out-col base

  // A fragments in registers for the whole kernel: 2 (r2) x 6 (kt)
  bf16x8 afr[2][6];
  #pragma unroll
  for (int r2 = 0; r2 < 2; ++r2)
    #pragma unroll
    for (int kt = 0; kt < 6; ++kt)
      afr[r2][kt] = *reinterpret_cast<const bf16x8*>(
          &A[(size_t)(rowBase + wr + r2 * 16 + lm) * 192 + kt * 32 + quad * 8]);

  uint4 rs1[6], rs2[6];
  // stage w1(0)
  #pragma unroll
  for (int i = 0; i < 6; ++i) {
    int seg = tid + i * 256, row = seg / 24, kk = (seg % 24) * 8;
    rs1[i] = *reinterpret_cast<const uint4*>(&W1t[(size_t)row * 192 + kk]);
  }
  #pragma unroll
  for (int i = 0; i < 6; ++i) {
    int seg = tid + i * 256, row = seg / 24, kk = (seg % 24) * 8;
    *reinterpret_cast<uint4*>(&W1B[row * 200 + kk]) = rs1[i];
  }
  // issue w2(0) loads (in flight across phase 1)
  #pragma unroll
  for (int i = 0; i < 6; ++i) {
    int seg = tid + i * 256, row = seg / 8, kk = (seg % 8) * 8;
    rs2[i] = *reinterpret_cast<const uint4*>(&W2t[(size_t)row * 768 + kk]);
  }
  __syncthreads();   // W1B visible

  f32x4 acc2[2][6] = {};
  for (int ht = 0; ht < 12; ++ht) {
    // ---- phase 1: hid(64x64) = A @ w1tile
    f32x4 acc1[2][2] = {};
    #pragma unroll
    for (int kt = 0; kt < 6; ++kt) {
      bf16x8 bfr[2];
      #pragma unroll
      for (int c2 = 0; c2 < 2; ++c2)
        bfr[c2] = *reinterpret_cast<const bf16x8*>(
            &W1B[(wc1 + c2 * 16 + lm) * 200 + kt * 32 + quad * 8]);
      #pragma unroll
      for (int r2 = 0; r2 < 2; ++r2)
        #pragma unroll
        for (int c2 = 0; c2 < 2; ++c2)
          acc1[r2][c2] = __builtin_amdgcn_mfma_f32_16x16x32_bf16(
              afr[r2][kt], bfr[c2], acc1[r2][c2], 0, 0, 0);
    }
    // gelu + b1, hid tile -> Hs
    #pragma unroll
    for (int r2 = 0; r2 < 2; ++r2)
      #pragma unroll
      for (int c2 = 0; c2 < 2; ++c2) {
        int col = wc1 + c2 * 16 + lm;
        float bb1 = b1[ht * 64 + col];
        #pragma unroll
        for (int g = 0; g < 4; ++g) {
          int row = wr + r2 * 16 + quad * 4 + g;
          Hs[row * 72 + col] = f2us(gelu_exact(acc1[r2][c2][g] + bb1));
        }
      }
    // w2 regs arrived; write W2B (prior readers done before entry barrier)
    #pragma unroll
    for (int i = 0; i < 6; ++i) {
      int seg = tid + i * 256, row = seg / 8, kk = (seg % 8) * 8;
      *reinterpret_cast<uint4*>(&W2B[row * 72 + kk]) = rs2[i];
    }
    // issue w1(ht+1) loads (hidden under phase 2)
    if (ht + 1 < 12) {
      #pragma unroll
      for (int i = 0; i < 6; ++i) {
        int seg = tid + i * 256, row = seg / 24, kk = (seg % 24) * 8;
        rs1[i] = *reinterpret_cast<const uint4*>(
            &W1t[(size_t)((ht + 1) * 64 + row) * 192 + kk]);
      }
    }
    __syncthreads();   // Hs + W2B visible; W1B reads complete
    // ---- phase 2: acc2 += hid @ w2tile
    #pragma unroll
    for (int s = 0; s < 2; ++s) {
      bf16x8 ap[2], bp[6];
      #pragma unroll
      for (int r2 = 0; r2 < 2; ++r2)
        ap[r2] = *reinterpret_cast<const bf16x8*>(
            &Hs[(wr + r2 * 16 + lm) * 72 + s * 32 + quad * 8]);
      #pragma unroll
      for (int c2 = 0; c2 < 6; ++c2)
        bp[c2] = *reinterpret_cast<const bf16x8*>(
            &W2B[(wc2 + c2 * 16 + lm) * 72 + s * 32 + quad * 8]);
      #pragma unroll
      for (int r2 = 0; r2 < 2; ++r2)
        #pragma unroll
        for (int c2 = 0; c2 < 6; ++c2)
          acc2[r2][c2] = __builtin_amdgcn_mfma_f32_16x16x32_bf16(
              ap[r2], bp[c2], acc2[r2][c2], 0, 0, 0);
    }
    if (ht + 1 < 12) {
      // w1 regs arrived; write W1B (readers finished at last barrier)
      #pragma unroll
      for (int i = 0; i < 6; ++i) {
        int seg = tid + i * 256, row = seg / 24, kk = (seg % 24) * 8;
        *reinterpret_cast<uint4*>(&W1B[row * 200 + kk]) = rs1[i];
      }
      // issue w2(ht+1) loads (hidden under next phase 1)
      #pragma unroll
      for (int i = 0; i < 6; ++i) {
        int seg = tid + i * 256, row = seg / 8, kk = (seg % 8) * 8;
        rs2[i] = *reinterpret_cast<const uint4*>(
            &W2t[(size_t)row * 768 + (ht + 1) * 64 + kk]);
      }
      __syncthreads();   // W1B ready; Hs/W2B reads done before next overwrite
    }
  }
  // ---- epilogue: + b2 + residual, write fp32 + bf16
  #pragma unroll
  for (int r2 = 0; r2 < 2; ++r2)
    #pragma unroll
    for (int c2 = 0; c2 < 6; ++c2) {
      int col = wc2 + c2 * 16 + lm;
      float bb2 = b2[col];
      #pragma unroll
      for (int g = 0; g < 4; ++g) {
        int row = rowBase + wr + r2 * 16 + quad * 4 + g;
        size_t idx = (size_t)row * 192 + col;
        float v = acc2[r2][c2][g] + bb2 + resF[idx];
        Cf[idx] = v;
        Cb[idx] = f2us(v);
      }
    }
}

// ---------- MFMA GEMM 128x64: BM=128 BN=64 BK=32, 4 waves (2x2) ----------
// Depth-2 pipelined: raw s_barrier, counted vmcnt(3) steady state.
template<int ACT, int RES, int OUTF, int OUTB, int BIAS>
__global__ __launch_bounds__(256)
void mgemm(const ushort* __restrict__ A, const ushort* __restrict__ Bt,
           const float* __restrict__ bias, const float* __restrict__ resF,
           float* __restrict__ Cf, ushort* __restrict__ Cb,
           int M, int N, int K)
{
  __shared__ __align__(16) ushort Asm[2][128 * 32];
  __shared__ __align__(16) ushort Bsm[2][64 * 32];
  const int tid = threadIdx.x;
  const int wave = tid >> 6, lane = tid & 63;
  const int quad = lane >> 4, lm = lane & 15;
  const int rowBase = blockIdx.y * 128, colBase = blockIdx.x * 64;
  const int wrow = (wave & 1) * 64, wcol = (wave >> 1) * 32;
  const int srow = lane >> 2, skcol = (lane & 3) * 8;
  const int nIter = K >> 5;

  auto stage = [&](int buf, int it) {
    const int k0 = it * 32;
    #pragma unroll
    for (int uu = 0; uu < 3; ++uu) {
      const int u = wave * 3 + uu;
      if (u < 8) {
        const ushort* gp = A + (size_t)(rowBase + u * 16 + srow) * K + k0 + skcol;
        gload16(gp, &Asm[buf][u * 512]);
      } else {
        const int v = u - 8;
        const ushort* gp = Bt + (size_t)(colBase + v * 16 + srow) * K + k0 + skcol;
        gload16(gp, &Bsm[buf][v * 512]);
      }
    }
  };

  f32x4 acc[4][2] = {};
  stage(0, 0);
  if (nIter > 1) stage(1, 1);

  for (int t = 0; t < nIter; ++t) {
    const int cur = t & 1;
    if (t + 1 < nIter) asm volatile("s_waitcnt vmcnt(3)" ::: "memory");
    else               asm volatile("s_waitcnt vmcnt(0)" ::: "memory");
    __builtin_amdgcn_s_barrier();
    bf16x8 af[4], bfr[2];
    #pragma unroll
    for (int r2 = 0; r2 < 4; ++r2)
      af[r2] = *reinterpret_cast<const bf16x8*>(&Asm[cur][(wrow + r2 * 16 + lm) * 32 + quad * 8]);
    #pragma unroll
    for (int c2 = 0; c2 < 2; ++c2)
      bfr[c2] = *reinterpret_cast<const bf16x8*>(&Bsm[cur][(wcol + c2 * 16 + lm) * 32 + quad * 8]);
    asm volatile("s_waitcnt lgkmcnt(0)" ::: "memory");
    __builtin_amdgcn_s_barrier();
    if (t + 2 < nIter) stage(cur, t + 2);
    #pragma unroll
    for (int r2 = 0; r2 < 4; ++r2)
      #pragma unroll
      for (int c2 = 0; c2 < 2; ++c2)
        acc[r2][c2] = __builtin_amdgcn_mfma_f32_16x16x32_bf16(af[r2], bfr[c2], acc[r2][c2], 0, 0, 0);
  }

  #pragma unroll
  for (int r2 = 0; r2 < 4; ++r2) {
    #pragma unroll
    for (int c2 = 0; c2 < 2; ++c2) {
      int col = colBase + wcol + c2 * 16 + lm;
      int row0 = rowBase + wrow + r2 * 16 + quad * 4;
      #pragma unroll
      for (int g = 0; g < 4; ++g) {
        float v = acc[r2][c2][g];
        size_t idx = (size_t)(row0 + g) * N + col;
        if (BIAS) v += bias[col];
        if (ACT == 1) v = gelu_exact(v);
        if (RES) v += resF[idx];
        if (OUTF) Cf[idx] = v;
        if (OUTB) Cb[idx] = f2us(v);
      }
    }
  }
}

// ---------- MFMA GEMM 128x128: BM=128 BN=128 BK=32, 4 waves each 64x64 ----------
template<int ACT, int RES, int OUTF, int OUTB, int BIAS, int SPLITK>
__global__ __launch_bounds__(256)
void mgemm128(const ushort* __restrict__ A, const ushort* __restrict__ Bt,
              const float* __restrict__ bias, const float* __restrict__ resF,
              float* __restrict__ Cf, ushort* __restrict__ Cb,
              int M, int N, int K, int kChunk)
{
  __shared__ __align__(16) ushort Asm[2][128 * 32];
  __shared__ __align__(16) ushort Bsm[2][128 * 32];
  const int tid = threadIdx.x;
  const int wave = tid >> 6, lane = tid & 63;
  const int quad = lane >> 4, lm = lane & 15;
  const int rowBase = blockIdx.y * 128, colBase = blockIdx.x * 128;
  const int wrow = (wave & 1) * 64, wcol = (wave >> 1) * 64;
  const int srow = lane >> 2, skcol = (lane & 3) * 8;

  const int kbeg = SPLITK ? blockIdx.z * kChunk : 0;
  const int nIter = (SPLITK ? kChunk : K) >> 5;

  auto stage = [&](int buf, int it) {
    const int k0 = kbeg + it * 32;
    #pragma unroll
    for (int uu = 0; uu < 4; ++uu) {
      const int u = wave * 4 + uu;
      if (u < 8) {
        const ushort* gp = A + (size_t)(rowBase + u * 16 + srow) * K + k0 + skcol;
        gload16(gp, &Asm[buf][u * 512]);
      } else {
        const int v = u - 8;
        const ushort* gp = Bt + (size_t)(colBase + v * 16 + srow) * K + k0 + skcol;
        gload16(gp, &Bsm[buf][v * 512]);
      }
    }
  };

  f32x4 acc[4][4] = {};
  stage(0, 0);
  if (nIter > 1) stage(1, 1);

  for (int t = 0; t < nIter; ++t) {
    const int cur = t & 1;
    if (t + 1 < nIter) asm volatile("s_waitcnt vmcnt(4)" ::: "memory");
    else               asm volatile("s_waitcnt vmcnt(0)" ::: "memory");
    __builtin_amdgcn_s_barrier();
    bf16x8 af[4], bfr[4];
    #pragma unroll
    for (int r2 = 0; r2 < 4; ++r2)
      af[r2] = *reinterpret_cast<const bf16x8*>(&Asm[cur][(wrow + r2 * 16 + lm) * 32 + quad * 8]);
    #pragma unroll
    for (int c2 = 0; c2 < 4; ++c2)
      bfr[c2] = *reinterpret_cast<const bf16x8*>(&Bsm[cur][(wcol + c2 * 16 + lm) * 32 + quad * 8]);
    asm volatile("s_waitcnt lgkmcnt(0)" ::: "memory");
    __builtin_amdgcn_s_barrier();
    if (t + 2 < nIter) stage(cur, t + 2);
    #pragma unroll
    for (int r2 = 0; r2 < 4; ++r2)
      #pragma unroll
      for (int c2 = 0; c2 < 4; ++c2)
        acc[r2][c2] = __builtin_amdgcn_mfma_f32_16x16x32_bf16(af[r2], bfr[c2], acc[r2][c2], 0, 0, 0);
  }

  const size_t zoff = SPLITK ? (size_t)blockIdx.z * M * N : 0;
  #pragma unroll
  for (int r2 = 0; r2 < 4; ++r2) {
    #pragma unroll
    for (int c2 = 0; c2 < 4; ++c2) {
      int col = colBase + wcol + c2 * 16 + lm;
      int row0 = rowBase + wrow + r2 * 16 + quad * 4;
      #pragma unroll
      for (int g = 0; g < 4; ++g) {
        float v = acc[r2][c2][g];
        size_t idx = (size_t)(row0 + g) * N + col;
        if (BIAS) v += bias[col];
        if (ACT == 1) v = gelu_exact(v);
        if (RES) v += resF[idx];
        if (OUTF) Cf[zoff + idx] = v;
        if (OUTB) Cb[idx] = f2us(v);
      }
    }
  }
}

// ---------- split-K reduce for zg: ZG = sum_8 P + bias ----------
__global__ __launch_bounds__(256)
void reduce8_kernel(const float* __restrict__ P, const float* __restrict__ db,
                    float* __restrict__ ZG)
{
  int i = blockIdx.x * 256 + threadIdx.x;
  float s = db[i % 768];
  #pragma unroll
  for (int k = 0; k < 8; ++k) s += P[i + k * 786432];
  ZG[i] = s;
}

// ---------- split-K reduce for global fc2: out = sum_4 P + bias + res ----------
__global__ __launch_bounds__(256)
void reduce4res_kernel(const float* __restrict__ P, const float* __restrict__ db,
                       const float* __restrict__ res, float* __restrict__ out)
{
  int i = blockIdx.x * 256 + threadIdx.x;   // 3072*768
  float s = db[i % 768] + res[i];
  #pragma unroll
  for (int k = 0; k < 4; ++k) s += P[i + k * 2359296];
  out[i] = s;
}

// ---------- MFMA fused attention: one block per (seq, head), causal ----------
template<int L, int HD, int NW>
__global__ __launch_bounds__(NW * 64)
void fattn(const ushort* __restrict__ QKV, ushort* __restrict__ Yp,
           int nh, int DS, int DY, int offQ, int offK, int offV)
{
  constexpr int PQ = HD + 8;
  constexpr int PV = L + 8;
  constexpr int KS = HD / 32;
  constexpr int NCT = L / 16;
  constexpr int KS2 = L / 32;
  constexpr int NYT = HD / 16;
  constexpr int T = NW * 64;
  __shared__ __align__(16) ushort Ql[L * PQ];
  __shared__ __align__(16) ushort Kl[L * PQ];
  __shared__ __align__(16) ushort Vt[HD * PV];
  __shared__ __align__(16) ushort Ps[L * PV];
  const int tid = threadIdx.x;
  const int b = blockIdx.x / nh, h = blockIdx.x % nh;
  const size_t rowb = (size_t)b * L * DS;
  const int hb = h * HD;
  constexpr int CH = L * HD / 8;
  for (int idx = tid; idx < CH; idx += T) {
    int row = idx / (HD / 8), seg = idx % (HD / 8);
    uint4 q4 = *reinterpret_cast<const uint4*>(&QKV[rowb + (size_t)row * DS + offQ + hb + seg * 8]);
    *reinterpret_cast<uint4*>(&Ql[row * PQ + seg * 8]) = q4;
    uint4 k4 = *reinterpret_cast<const uint4*>(&QKV[rowb + (size_t)row * DS + offK + hb + seg * 8]);
    *reinterpret_cast<uint4*>(&Kl[row * PQ + seg * 8]) = k4;
  }
  for (int idx = tid; idx < L * HD; idx += T) {
    int j = idx / HD, d = idx % HD;
    Vt[d * PV + j] = QKV[rowb + (size_t)j * DS + offV + hb + d];
  }
  __syncthreads();
  const int lane = tid & 63;
  const int quad = lane >> 4, lm = lane & 15;
  const int rt = tid >> 6;
  const float scale = rsqrtf((float)HD);
  bf16x8 af[KS];
  #pragma unroll
  for (int s = 0; s < KS; ++s)
    af[s] = *reinterpret_cast<const bf16x8*>(&Ql[(rt * 16 + lm) * PQ + s * 32 + quad * 8]);
  f32x4 sacc[NCT] = {};
  #pragma unroll
  for (int ct = 0; ct < NCT; ++ct)
    #pragma unroll
    for (int s = 0; s < KS; ++s) {
      bf16x8 bf = *reinterpret_cast<const bf16x8*>(&Kl[(ct * 16 + lm) * PQ + s * 32 + quad * 8]);
      sacc[ct] = __builtin_amdgcn_mfma_f32_16x16x32_bf16(af[s], bf, sacc[ct], 0, 0, 0);
    }
  float inv[4];
  #pragma unroll
  for (int g = 0; g < 4; ++g) {
    const int row = rt * 16 + quad * 4 + g;
    float sv[NCT]; float m = -1e30f;
    #pragma unroll
    for (int ct = 0; ct < NCT; ++ct) {
      int col = ct * 16 + lm;
      float x = sacc[ct][g] * scale;
      sv[ct] = (col <= row) ? x : -1e30f;
      m = fmaxf(m, sv[ct]);
    }
    #pragma unroll
    for (int off = 8; off >= 1; off >>= 1) m = fmaxf(m, __shfl_xor(m, off));
    float l = 0.f;
    #pragma unroll
    for (int ct = 0; ct < NCT; ++ct) {
      float p = __expf(sv[ct] - m);
      l += p;
      Ps[row * PV + ct * 16 + lm] = f2us(p);
    }
    #pragma unroll
    for (int off = 8; off >= 1; off >>= 1) l += __shfl_xor(l, off);
    inv[g] = 1.f / l;
  }
  __syncthreads();
  f32x4 yacc[NYT] = {};
  #pragma unroll
  for (int s = 0; s < KS2; ++s) {
    bf16x8 ap = *reinterpret_cast<const bf16x8*>(&Ps[(rt * 16 + lm) * PV + s * 32 + quad * 8]);
    #pragma unroll
    for (int ct = 0; ct < NYT; ++ct) {
      bf16x8 bv = *reinterpret_cast<const bf16x8*>(&Vt[(ct * 16 + lm) * PV + s * 32 + quad * 8]);
      yacc[ct] = __builtin_amdgcn_mfma_f32_16x16x32_bf16(ap, bv, yacc[ct], 0, 0, 0);
    }
  }
  #pragma unroll
  for (int ct = 0; ct < NYT; ++ct)
    #pragma unroll
    for (int g = 0; g < 4; ++g) {
      int row = rt * 16 + quad * 4 + g;
      int d = ct * 16 + lm;
      Yp[((size_t)b * L + row) * DY + hb + d] = f2us(yacc[ct][g] * inv[g]);
    }
}

// ---------- zg interleave (fp32) ----------
__global__ __launch_bounds__(256)
void interleave_kernel(const float* __restrict__ zg, const float* __restrict__ xg,
                       float* __restrict__ z)
{
  int idx = blockIdx.x * 256 + threadIdx.x;
  int c = idx % 768;
  int tok = idx / 768;
  int b = tok / 96, r = tok % 96;
  int n = r / 3, t = r % 3;
  z[idx] = (t == 0) ? zg[((size_t)b * 32 + n) * 768 + c]
                    : xg[((size_t)b * 64 + 2 * n + (t - 1)) * 768 + c];
}

// ---------- final gather (fp32) ----------
__global__ __launch_bounds__(256)
void gather_kernel(const float* __restrict__ zfin, float* __restrict__ dst)
{
  int idx = blockIdx.x * 256 + threadIdx.x;
  int c = idx % 768;
  int t = (idx / 768) % 64;
  int b = idx / (768 * 64);
  int n = t >> 1, s = t & 1;
  dst[idx] = zfin[((size_t)b * 96 + 3 * n + 1 + s) * 768 + c];
}

extern "C" void kernel_launch(void* const* d_in, const int* in_sizes, int n_in,
                              void* d_out, int out_size, void* d_ws, size_t ws_size,
                              hipStream_t stream) {
  const float* xl = (const float*)d_in[0];
  const float* xg = (const float*)d_in[1];
  const float* l_ln1_w = (const float*)d_in[2];  const float* l_ln1_b = (const float*)d_in[3];
  const float* l_ln2_w = (const float*)d_in[4];  const float* l_ln2_b = (const float*)d_in[5];
  const float* l_wq = (const float*)d_in[6];     const float* l_bq = (const float*)d_in[7];
  const float* l_wk = (const float*)d_in[8];     const float* l_bk = (const float*)d_in[9];
  const float* l_wv = (const float*)d_in[10];    const float* l_bv = (const float*)d_in[11];
  const float* l_wo = (const float*)d_in[12];    const float* l_bo = (const float*)d_in[13];
  const float* l_w1 = (const float*)d_in[14];    const float* l_b1 = (const float*)d_in[15];
  const float* l_w2 = (const float*)d_in[16];    const float* l_b2 = (const float*)d_in[17];
  const float* g_ln1_w = (const float*)d_in[18]; const float* g_ln1_b = (const float*)d_in[19];
  const float* g_ln2_w = (const float*)d_in[20]; const float* g_ln2_b = (const float*)d_in[21];
  const float* g_wq = (const float*)d_in[22];    const float* g_bq = (const float*)d_in[23];
  const float* g_wk = (const float*)d_in[24];    const float* g_bk = (const float*)d_in[25];
  const float* g_wv = (const float*)d_in[26];    const float* g_bv = (const float*)d_in[27];
  const float* g_wo = (const float*)d_in[28];    const float* g_bo = (const float*)d_in[29];
  const float* g_w1 = (const float*)d_in[30];    const float* g_b1 = (const float*)d_in[31];
  const float* g_w2 = (const float*)d_in[32];    const float* g_b2 = (const float*)d_in[33];
  const float* dw   = (const float*)d_in[34];    const float* db   = (const float*)d_in[35];

  float* outL = (float*)d_out;
  float* outG = outL + 12582912;

  char* W = (char*)d_ws;
  ushort* A_bf   = (ushort*)(W + 0);
  ushort* QKVl   = (ushort*)(W + 25165824);
  ushort* XLb    = (ushort*)(W + 75497472);
  float*  X1     = (float*)(W + 100663296);
  ushort* wqkv_t = (ushort*)(W + 150994944);
  ushort* wo_t   = (ushort*)(W + 151216128);
  ushort* w1_t   = (ushort*)(W + 151289856);
  ushort* w2_t   = (ushort*)(W + 151584768);
  ushort* wd_t   = (ushort*)(W + 151879680);
  ushort* wgqkv_t= (ushort*)(W + 170754048);
  ushort* wgo_t  = (ushort*)(W + 174292992);
  ushort* wg1_t  = (ushort*)(W + 175472640);
  ushort* wg2_t  = (ushort*)(W + 180191232);
  float*  bqkv_l = (float*)(W + 184909824);
  float*  bqkv_g = (float*)(W + 184912128);
  // global-phase overlays
  float*  ZGP  = (float*)(W + 0);              // zg partials [8][1024*768]
  float*  FC2P = (float*)(W + 0);              // fc2 partials [4][3072*768] (after Z dead)
  float*  ZG   = (float*)(W + 25165824);
  float*  Z    = (float*)(W + 28311552);
  ushort* LNG  = (ushort*)(W + 37748736);
  ushort* QKVg = (ushort*)(W + 42467328);
  ushort* YG   = (ushort*)(W + 56623104);
  float*  X1G  = (float*)(W + 61341696);
  ushort* HLNG = (ushort*)(W + 70778880);
  ushort* HIDg = (ushort*)(W + 100663296);
  float*  OUTG = (float*)(W + 119537664);

  // ---- weight conversion (1 launch) + bias packs ----
  TJobs tj;
  tj.s[0] = l_wq; tj.s[1] = l_wk; tj.s[2] = l_wv; tj.s[3] = l_wo;
  tj.s[4] = l_w1; tj.s[5] = l_w2; tj.s[6] = dw;
  tj.s[7] = g_wq; tj.s[8] = g_wk; tj.s[9] = g_wv; tj.s[10] = g_wo;
  tj.s[11] = g_w1; tj.s[12] = g_w2;
  tj.d[0] = wqkv_t; tj.d[1] = wqkv_t; tj.d[2] = wqkv_t; tj.d[3] = wo_t;
  tj.d[4] = w1_t; tj.d[5] = w2_t; tj.d[6] = wd_t;
  tj.d[7] = wgqkv_t; tj.d[8] = wgqkv_t; tj.d[9] = wgqkv_t; tj.d[10] = wgo_t;
  tj.d[11] = wg1_t; tj.d[12] = wg2_t;
  transp_all<<<4140, 256, 0, stream>>>(tj);
  pack3_kernel<<<3, 256, 0, stream>>>(bqkv_l, l_bq, 192, l_bk, 192, l_bv, 192);
  pack3_kernel<<<9, 256, 0, stream>>>(bqkv_g, g_bq, 768, g_bk, 768, g_bv, 768);

  // ---- local block ----
  ln_kernel<192><<<16384, 256, 0, stream>>>(xl, l_ln1_w, l_ln1_b, A_bf, 65536);
  mgemm<0,0,0,1,1><<<dim3(9,512), 256, 0, stream>>>(A_bf, wqkv_t, bqkv_l, nullptr, nullptr, QKVl, 65536, 576, 192);
  fattn<64,32,4><<<6144, 256, 0, stream>>>(QKVl, A_bf, 6, 576, 192, 0, 192, 384);
  mgemm<0,1,1,0,1><<<dim3(3,512), 256, 0, stream>>>(A_bf, wo_t, l_bo, xl, X1, nullptr, 65536, 192, 192);
  ln_kernel<192><<<16384, 256, 0, stream>>>(X1, l_ln2_w, l_ln2_b, A_bf, 65536);
  fused_mlp<<<1024, 256, 0, stream>>>(A_bf, w1_t, w2_t, l_b1, l_b2, X1, outL, XLb);
  // ---- group summary projection (128-tile, split-K=8) + interleave ----
  mgemm128<0,0,1,0,0,1><<<dim3(6,8,8), 256, 0, stream>>>(XLb, wd_t, nullptr, nullptr, ZGP, nullptr, 1024, 768, 12288, 1536);
  reduce8_kernel<<<3072, 256, 0, stream>>>(ZGP, db, ZG);
  interleave_kernel<<<9216, 256, 0, stream>>>(ZG, xg, Z);
  // ---- global block ----
  ln_kernel<768><<<768, 256, 0, stream>>>(Z, g_ln1_w, g_ln1_b, LNG, 3072);
  mgemm128<0,0,0,1,1,0><<<dim3(18,24), 256, 0, stream>>>(LNG, wgqkv_t, bqkv_g, nullptr, nullptr, QKVg, 3072, 2304, 768, 0);
  fattn<96,64,6><<<384, 384, 0, stream>>>(QKVg, YG, 12, 2304, 768, 0, 768, 1536);
  mgemm<0,1,1,0,1><<<dim3(12,24), 256, 0, stream>>>(YG, wgo_t, g_bo, Z, X1G, nullptr, 3072, 768, 768);
  ln_kernel<768><<<768, 256, 0, stream>>>(X1G, g_ln2_w, g_ln2_b, HLNG, 3072);
  mgemm128<1,0,0,1,1,0><<<dim3(24,24), 256, 0, stream>>>(HLNG, wg1_t, g_b1, nullptr, nullptr, HIDg, 3072, 3072, 768, 0);
  mgemm128<0,0,1,0,0,1><<<dim3(6,24,4), 256, 0, stream>>>(HIDg, wg2_t, nullptr, nullptr, FC2P, nullptr, 3072, 768, 3072, 768);
  reduce4res_kernel<<<9216, 256, 0, stream>>>(FC2P, g_b2, X1G, OUTG);
  gather_kernel<<<6144, 256, 0, stream>>>(OUTG, outG);
}

// Round 5
// 699.037 us; speedup vs baseline: 1.0736x; 1.0736x over previous
//
#include <hip/hip_runtime.h>
#include <hip/hip_bf16.h>

// StARformer round 8: fused_mlp v2. Rounds 6/7 showed the uint4 staging
// arrays (written/read across barriers + loop iters under guards) defeat
// SROA -> structural scratch -> 574 MB writes, regardless of VGPR budget.
// v2 removes ALL reg/LDS weight staging: W1/W2 MFMA fragments are loaded
// directly from global (L2-resident, 2.4 MB total); only Hs (hid transpose)
// stays in LDS (9 KB -> 3-4 blocks/CU). All frag arrays are straight-line
// def-use, the same pattern mgemm/fattn compile cleanly.

typedef unsigned short ushort;
typedef __bf16 bf16x8 __attribute__((ext_vector_type(8)));
typedef float f32x4 __attribute__((ext_vector_type(4)));

__device__ __forceinline__ ushort f2us(float f) {
  __hip_bfloat16 h = __float2bfloat16(f);
  return *reinterpret_cast<ushort*>(&h);
}
__device__ __forceinline__ float gelu_exact(float v) {
  return 0.5f * v * (1.f + erff(v * 0.70710678118654752f));
}
__device__ __forceinline__ void gload16(const ushort* g, ushort* l) {
  __builtin_amdgcn_global_load_lds(
      (const __attribute__((address_space(1))) void*)g,
      (__attribute__((address_space(3))) void*)l, 16, 0, 0);
}

// ---------- batched transpose+convert: 13 weight jobs in one launch ----------
struct TJobs { const float* s[13]; ushort* d[13]; };

__global__ __launch_bounds__(256)
void transp_all(TJobs J)
{
  static constexpr int NN[13]  = {192,192,192,192,768,192,768,768,768,768,768,3072,768};
  static constexpr int SS[13]  = {192,192,192,192,192,768,12288,768,768,768,768,768,3072};
  static constexpr int RO[13]  = {0,192,384,0,0,0,0,0,768,1536,0,0,0};
  static constexpr int CUM[14] = {0,9,18,27,36,72,108,2412,2556,2700,2844,2988,3564,4140};
  __shared__ float t[64][65];
  int bid = blockIdx.x;
  int j = 0;
  while (bid >= CUM[j + 1]) ++j;
  int tIdx = bid - CUM[j];
  const int N = NN[j], stride = SS[j], rowOff = RO[j];
  const int nx = N >> 6;
  const int n0 = (tIdx % nx) * 64, k0 = (tIdx / nx) * 64;
  const float* W = J.s[j];
  ushort* Wt = J.d[j];
  int c = threadIdx.x & 63, r = threadIdx.x >> 6;
  #pragma unroll
  for (int i = 0; i < 16; ++i) {
    int kr = r + i * 4;
    t[kr][c] = W[(size_t)(k0 + kr) * N + n0 + c];
  }
  __syncthreads();
  #pragma unroll
  for (int i = 0; i < 16; ++i) {
    int nr = r + i * 4;
    Wt[(size_t)(rowOff + n0 + nr) * stride + k0 + c] = f2us(t[c][nr]);
  }
}

// ---------- pack 3 bias vectors ----------
__global__ __launch_bounds__(256)
void pack3_kernel(float* dst, const float* a, int na, const float* b, int nb,
                  const float* c, int nc)
{
  int i = blockIdx.x * 256 + threadIdx.x;
  if (i >= na + nb + nc) return;
  dst[i] = (i < na) ? a[i] : (i < na + nb ? b[i - na] : c[i - na - nb]);
}

// ---------- LayerNorm: one wave per row, fp32 in, bf16 out ----------
template<int D>
__global__ __launch_bounds__(256)
void ln_kernel(const float* __restrict__ x, const float* __restrict__ g,
               const float* __restrict__ bb, ushort* __restrict__ out, int rows)
{
  int wave = threadIdx.x >> 6, lane = threadIdx.x & 63;
  int row = blockIdx.x * 4 + wave;
  if (row >= rows) return;
  const float* xr = x + (size_t)row * D;
  constexpr int E = D / 64;
  float vals[E];
  float s = 0.f;
  #pragma unroll
  for (int e = 0; e < E; ++e) { vals[e] = xr[e * 64 + lane]; s += vals[e]; }
  #pragma unroll
  for (int off = 32; off >= 1; off >>= 1) s += __shfl_xor(s, off);
  float m = s * (1.f / D);
  float s2 = 0.f;
  #pragma unroll
  for (int e = 0; e < E; ++e) { float d = vals[e] - m; s2 += d * d; }
  #pragma unroll
  for (int off = 32; off >= 1; off >>= 1) s2 += __shfl_xor(s2, off);
  float rstd = rsqrtf(s2 * (1.f / D) + 1e-5f);
  ushort* orow = out + (size_t)row * D;
  #pragma unroll
  for (int e = 0; e < E; ++e) {
    int c = e * 64 + lane;
    orow[c] = f2us((vals[e] - m) * rstd * g[c] + bb[c]);
  }
}

// ---------- fused local MLP v2: out = res + b2 + gelu(A@w1 + b1) @ w2 ----------
// Per block: 64 rows. A frags in regs; W1/W2 frags read directly from global
// (L2-resident); only the hid-tile transpose (Hs) goes through LDS.
__global__ __launch_bounds__(256, 2)
void fused_mlp(const ushort* __restrict__ A, const ushort* __restrict__ W1t,
               const ushort* __restrict__ W2t, const float* __restrict__ b1,
               const float* __restrict__ b2, const float* __restrict__ resF,
               float* __restrict__ Cf, ushort* __restrict__ Cb)
{
  __shared__ __align__(16) ushort Hs[64 * 72];     // hid tile [64 r][64 k], pad 72
  const int tid = threadIdx.x;
  const int wave = tid >> 6, lane = tid & 63;
  const int quad = lane >> 4, lm = lane & 15;
  const int rowBase = blockIdx.x * 64;
  const int wr  = (wave & 1) * 32;     // row base (both phases)
  const int wc1 = (wave >> 1) * 32;    // phase1 hid-col base
  const int wc2 = (wave >> 1) * 96;    // phase2 out-col base

  // A fragments in registers for the whole kernel: 2 (r2) x 6 (kt)
  bf16x8 afr[2][6];
  #pragma unroll
  for (int r2 = 0; r2 < 2; ++r2)
    #pragma unroll
    for (int kt = 0; kt < 6; ++kt)
      afr[r2][kt] = *reinterpret_cast<const bf16x8*>(
          &A[(size_t)(rowBase + wr + r2 * 16 + lm) * 192 + kt * 32 + quad * 8]);

  f32x4 acc2[2][6] = {};
  for (int ht = 0; ht < 12; ++ht) {
    // ---- phase 1: hid(64x64) = A @ w1tile; B-frags direct from global
    f32x4 acc1[2][2] = {};
    #pragma unroll
    for (int kt = 0; kt < 6; ++kt) {
      bf16x8 bfr[2];
      #pragma unroll
      for (int c2 = 0; c2 < 2; ++c2)
        bfr[c2] = *reinterpret_cast<const bf16x8*>(
            &W1t[(size_t)(ht * 64 + wc1 + c2 * 16 + lm) * 192 + kt * 32 + quad * 8]);
      #pragma unroll
      for (int r2 = 0; r2 < 2; ++r2)
        #pragma unroll
        for (int c2 = 0; c2 < 2; ++c2)
          acc1[r2][c2] = __builtin_amdgcn_mfma_f32_16x16x32_bf16(
              afr[r2][kt], bfr[c2], acc1[r2][c2], 0, 0, 0);
    }
    __syncthreads();   // previous iteration's phase-2 Hs reads complete
    // gelu + b1, hid tile -> Hs
    #pragma unroll
    for (int r2 = 0; r2 < 2; ++r2)
      #pragma unroll
      for (int c2 = 0; c2 < 2; ++c2) {
        int col = wc1 + c2 * 16 + lm;
        float bb1 = b1[ht * 64 + col];
        #pragma unroll
        for (int g = 0; g < 4; ++g) {
          int row = wr + r2 * 16 + quad * 4 + g;
          Hs[row * 72 + col] = f2us(gelu_exact(acc1[r2][c2][g] + bb1));
        }
      }
    __syncthreads();   // Hs visible
    // ---- phase 2: acc2 += hid @ w2tile; B-frags direct from global
    #pragma unroll
    for (int s = 0; s < 2; ++s) {
      bf16x8 ap[2], bp[6];
      #pragma unroll
      for (int r2 = 0; r2 < 2; ++r2)
        ap[r2] = *reinterpret_cast<const bf16x8*>(
            &Hs[(wr + r2 * 16 + lm) * 72 + s * 32 + quad * 8]);
      #pragma unroll
      for (int c2 = 0; c2 < 6; ++c2)
        bp[c2] = *reinterpret_cast<const bf16x8*>(
            &W2t[(size_t)(wc2 + c2 * 16 + lm) * 768 + ht * 64 + s * 32 + quad * 8]);
      #pragma unroll
      for (int r2 = 0; r2 < 2; ++r2)
        #pragma unroll
        for (int c2 = 0; c2 < 6; ++c2)
          acc2[r2][c2] = __builtin_amdgcn_mfma_f32_16x16x32_bf16(
              ap[r2], bp[c2], acc2[r2][c2], 0, 0, 0);
    }
  }
  // ---- epilogue: + b2 + residual, write fp32 + bf16
  #pragma unroll
  for (int r2 = 0; r2 < 2; ++r2)
    #pragma unroll
    for (int c2 = 0; c2 < 6; ++c2) {
      int col = wc2 + c2 * 16 + lm;
      float bb2 = b2[col];
      #pragma unroll
      for (int g = 0; g < 4; ++g) {
        int row = rowBase + wr + r2 * 16 + quad * 4 + g;
        size_t idx = (size_t)row * 192 + col;
        float v = acc2[r2][c2][g] + bb2 + resF[idx];
        Cf[idx] = v;
        Cb[idx] = f2us(v);
      }
    }
}

// ---------- MFMA GEMM 128x64: BM=128 BN=64 BK=32, 4 waves (2x2) ----------
// Depth-2 pipelined: raw s_barrier, counted vmcnt(3) steady state.
template<int ACT, int RES, int OUTF, int OUTB, int BIAS>
__global__ __launch_bounds__(256)
void mgemm(const ushort* __restrict__ A, const ushort* __restrict__ Bt,
           const float* __restrict__ bias, const float* __restrict__ resF,
           float* __restrict__ Cf, ushort* __restrict__ Cb,
           int M, int N, int K)
{
  __shared__ __align__(16) ushort Asm[2][128 * 32];
  __shared__ __align__(16) ushort Bsm[2][64 * 32];
  const int tid = threadIdx.x;
  const int wave = tid >> 6, lane = tid & 63;
  const int quad = lane >> 4, lm = lane & 15;
  const int rowBase = blockIdx.y * 128, colBase = blockIdx.x * 64;
  const int wrow = (wave & 1) * 64, wcol = (wave >> 1) * 32;
  const int srow = lane >> 2, skcol = (lane & 3) * 8;
  const int nIter = K >> 5;

  auto stage = [&](int buf, int it) {
    const int k0 = it * 32;
    #pragma unroll
    for (int uu = 0; uu < 3; ++uu) {
      const int u = wave * 3 + uu;
      if (u < 8) {
        const ushort* gp = A + (size_t)(rowBase + u * 16 + srow) * K + k0 + skcol;
        gload16(gp, &Asm[buf][u * 512]);
      } else {
        const int v = u - 8;
        const ushort* gp = Bt + (size_t)(colBase + v * 16 + srow) * K + k0 + skcol;
        gload16(gp, &Bsm[buf][v * 512]);
      }
    }
  };

  f32x4 acc[4][2] = {};
  stage(0, 0);
  if (nIter > 1) stage(1, 1);

  for (int t = 0; t < nIter; ++t) {
    const int cur = t & 1;
    if (t + 1 < nIter) asm volatile("s_waitcnt vmcnt(3)" ::: "memory");
    else               asm volatile("s_waitcnt vmcnt(0)" ::: "memory");
    __builtin_amdgcn_s_barrier();
    bf16x8 af[4], bfr[2];
    #pragma unroll
    for (int r2 = 0; r2 < 4; ++r2)
      af[r2] = *reinterpret_cast<const bf16x8*>(&Asm[cur][(wrow + r2 * 16 + lm) * 32 + quad * 8]);
    #pragma unroll
    for (int c2 = 0; c2 < 2; ++c2)
      bfr[c2] = *reinterpret_cast<const bf16x8*>(&Bsm[cur][(wcol + c2 * 16 + lm) * 32 + quad * 8]);
    asm volatile("s_waitcnt lgkmcnt(0)" ::: "memory");
    __builtin_amdgcn_s_barrier();
    if (t + 2 < nIter) stage(cur, t + 2);
    #pragma unroll
    for (int r2 = 0; r2 < 4; ++r2)
      #pragma unroll
      for (int c2 = 0; c2 < 2; ++c2)
        acc[r2][c2] = __builtin_amdgcn_mfma_f32_16x16x32_bf16(af[r2], bfr[c2], acc[r2][c2], 0, 0, 0);
  }

  #pragma unroll
  for (int r2 = 0; r2 < 4; ++r2) {
    #pragma unroll
    for (int c2 = 0; c2 < 2; ++c2) {
      int col = colBase + wcol + c2 * 16 + lm;
      int row0 = rowBase + wrow + r2 * 16 + quad * 4;
      #pragma unroll
      for (int g = 0; g < 4; ++g) {
        float v = acc[r2][c2][g];
        size_t idx = (size_t)(row0 + g) * N + col;
        if (BIAS) v += bias[col];
        if (ACT == 1) v = gelu_exact(v);
        if (RES) v += resF[idx];
        if (OUTF) Cf[idx] = v;
        if (OUTB) Cb[idx] = f2us(v);
      }
    }
  }
}

// ---------- MFMA GEMM 128x128: BM=128 BN=128 BK=32, 4 waves each 64x64 ----------
template<int ACT, int RES, int OUTF, int OUTB, int BIAS, int SPLITK>
__global__ __launch_bounds__(256)
void mgemm128(const ushort* __restrict__ A, const ushort* __restrict__ Bt,
              const float* __restrict__ bias, const float* __restrict__ resF,
              float* __restrict__ Cf, ushort* __restrict__ Cb,
              int M, int N, int K, int kChunk)
{
  __shared__ __align__(16) ushort Asm[2][128 * 32];
  __shared__ __align__(16) ushort Bsm[2][128 * 32];
  const int tid = threadIdx.x;
  const int wave = tid >> 6, lane = tid & 63;
  const int quad = lane >> 4, lm = lane & 15;
  const int rowBase = blockIdx.y * 128, colBase = blockIdx.x * 128;
  const int wrow = (wave & 1) * 64, wcol = (wave >> 1) * 64;
  const int srow = lane >> 2, skcol = (lane & 3) * 8;

  const int kbeg = SPLITK ? blockIdx.z * kChunk : 0;
  const int nIter = (SPLITK ? kChunk : K) >> 5;

  auto stage = [&](int buf, int it) {
    const int k0 = kbeg + it * 32;
    #pragma unroll
    for (int uu = 0; uu < 4; ++uu) {
      const int u = wave * 4 + uu;
      if (u < 8) {
        const ushort* gp = A + (size_t)(rowBase + u * 16 + srow) * K + k0 + skcol;
        gload16(gp, &Asm[buf][u * 512]);
      } else {
        const int v = u - 8;
        const ushort* gp = Bt + (size_t)(colBase + v * 16 + srow) * K + k0 + skcol;
        gload16(gp, &Bsm[buf][v * 512]);
      }
    }
  };

  f32x4 acc[4][4] = {};
  stage(0, 0);
  if (nIter > 1) stage(1, 1);

  for (int t = 0; t < nIter; ++t) {
    const int cur = t & 1;
    if (t + 1 < nIter) asm volatile("s_waitcnt vmcnt(4)" ::: "memory");
    else               asm volatile("s_waitcnt vmcnt(0)" ::: "memory");
    __builtin_amdgcn_s_barrier();
    bf16x8 af[4], bfr[4];
    #pragma unroll
    for (int r2 = 0; r2 < 4; ++r2)
      af[r2] = *reinterpret_cast<const bf16x8*>(&Asm[cur][(wrow + r2 * 16 + lm) * 32 + quad * 8]);
    #pragma unroll
    for (int c2 = 0; c2 < 4; ++c2)
      bfr[c2] = *reinterpret_cast<const bf16x8*>(&Bsm[cur][(wcol + c2 * 16 + lm) * 32 + quad * 8]);
    asm volatile("s_waitcnt lgkmcnt(0)" ::: "memory");
    __builtin_amdgcn_s_barrier();
    if (t + 2 < nIter) stage(cur, t + 2);
    #pragma unroll
    for (int r2 = 0; r2 < 4; ++r2)
      #pragma unroll
      for (int c2 = 0; c2 < 4; ++c2)
        acc[r2][c2] = __builtin_amdgcn_mfma_f32_16x16x32_bf16(af[r2], bfr[c2], acc[r2][c2], 0, 0, 0);
  }

  const size_t zoff = SPLITK ? (size_t)blockIdx.z * M * N : 0;
  #pragma unroll
  for (int r2 = 0; r2 < 4; ++r2) {
    #pragma unroll
    for (int c2 = 0; c2 < 4; ++c2) {
      int col = colBase + wcol + c2 * 16 + lm;
      int row0 = rowBase + wrow + r2 * 16 + quad * 4;
      #pragma unroll
      for (int g = 0; g < 4; ++g) {
        float v = acc[r2][c2][g];
        size_t idx = (size_t)(row0 + g) * N + col;
        if (BIAS) v += bias[col];
        if (ACT == 1) v = gelu_exact(v);
        if (RES) v += resF[idx];
        if (OUTF) Cf[zoff + idx] = v;
        if (OUTB) Cb[idx] = f2us(v);
      }
    }
  }
}

// ---------- split-K reduce for zg: ZG = sum_8 P + bias ----------
__global__ __launch_bounds__(256)
void reduce8_kernel(const float* __restrict__ P, const float* __restrict__ db,
                    float* __restrict__ ZG)
{
  int i = blockIdx.x * 256 + threadIdx.x;
  float s = db[i % 768];
  #pragma unroll
  for (int k = 0; k < 8; ++k) s += P[i + k * 786432];
  ZG[i] = s;
}

// ---------- split-K reduce for global fc2: out = sum_4 P + bias + res ----------
__global__ __launch_bounds__(256)
void reduce4res_kernel(const float* __restrict__ P, const float* __restrict__ db,
                       const float* __restrict__ res, float* __restrict__ out)
{
  int i = blockIdx.x * 256 + threadIdx.x;   // 3072*768
  float s = db[i % 768] + res[i];
  #pragma unroll
  for (int k = 0; k < 4; ++k) s += P[i + k * 2359296];
  out[i] = s;
}

// ---------- MFMA fused attention: one block per (seq, head), causal ----------
template<int L, int HD, int NW>
__global__ __launch_bounds__(NW * 64)
void fattn(const ushort* __restrict__ QKV, ushort* __restrict__ Yp,
           int nh, int DS, int DY, int offQ, int offK, int offV)
{
  constexpr int PQ = HD + 8;
  constexpr int PV = L + 8;
  constexpr int KS = HD / 32;
  constexpr int NCT = L / 16;
  constexpr int KS2 = L / 32;
  constexpr int NYT = HD / 16;
  constexpr int T = NW * 64;
  __shared__ __align__(16) ushort Ql[L * PQ];
  __shared__ __align__(16) ushort Kl[L * PQ];
  __shared__ __align__(16) ushort Vt[HD * PV];
  __shared__ __align__(16) ushort Ps[L * PV];
  const int tid = threadIdx.x;
  const int b = blockIdx.x / nh, h = blockIdx.x % nh;
  const size_t rowb = (size_t)b * L * DS;
  const int hb = h * HD;
  constexpr int CH = L * HD / 8;
  for (int idx = tid; idx < CH; idx += T) {
    int row = idx / (HD / 8), seg = idx % (HD / 8);
    uint4 q4 = *reinterpret_cast<const uint4*>(&QKV[rowb + (size_t)row * DS + offQ + hb + seg * 8]);
    *reinterpret_cast<uint4*>(&Ql[row * PQ + seg * 8]) = q4;
    uint4 k4 = *reinterpret_cast<const uint4*>(&QKV[rowb + (size_t)row * DS + offK + hb + seg * 8]);
    *reinterpret_cast<uint4*>(&Kl[row * PQ + seg * 8]) = k4;
  }
  for (int idx = tid; idx < L * HD; idx += T) {
    int j = idx / HD, d = idx % HD;
    Vt[d * PV + j] = QKV[rowb + (size_t)j * DS + offV + hb + d];
  }
  __syncthreads();
  const int lane = tid & 63;
  const int quad = lane >> 4, lm = lane & 15;
  const int rt = tid >> 6;
  const float scale = rsqrtf((float)HD);
  bf16x8 af[KS];
  #pragma unroll
  for (int s = 0; s < KS; ++s)
    af[s] = *reinterpret_cast<const bf16x8*>(&Ql[(rt * 16 + lm) * PQ + s * 32 + quad * 8]);
  f32x4 sacc[NCT] = {};
  #pragma unroll
  for (int ct = 0; ct < NCT; ++ct)
    #pragma unroll
    for (int s = 0; s < KS; ++s) {
      bf16x8 bf = *reinterpret_cast<const bf16x8*>(&Kl[(ct * 16 + lm) * PQ + s * 32 + quad * 8]);
      sacc[ct] = __builtin_amdgcn_mfma_f32_16x16x32_bf16(af[s], bf, sacc[ct], 0, 0, 0);
    }
  float inv[4];
  #pragma unroll
  for (int g = 0; g < 4; ++g) {
    const int row = rt * 16 + quad * 4 + g;
    float sv[NCT]; float m = -1e30f;
    #pragma unroll
    for (int ct = 0; ct < NCT; ++ct) {
      int col = ct * 16 + lm;
      float x = sacc[ct][g] * scale;
      sv[ct] = (col <= row) ? x : -1e30f;
      m = fmaxf(m, sv[ct]);
    }
    #pragma unroll
    for (int off = 8; off >= 1; off >>= 1) m = fmaxf(m, __shfl_xor(m, off));
    float l = 0.f;
    #pragma unroll
    for (int ct = 0; ct < NCT; ++ct) {
      float p = __expf(sv[ct] - m);
      l += p;
      Ps[row * PV + ct * 16 + lm] = f2us(p);
    }
    #pragma unroll
    for (int off = 8; off >= 1; off >>= 1) l += __shfl_xor(l, off);
    inv[g] = 1.f / l;
  }
  __syncthreads();
  f32x4 yacc[NYT] = {};
  #pragma unroll
  for (int s = 0; s < KS2; ++s) {
    bf16x8 ap = *reinterpret_cast<const bf16x8*>(&Ps[(rt * 16 + lm) * PV + s * 32 + quad * 8]);
    #pragma unroll
    for (int ct = 0; ct < NYT; ++ct) {
      bf16x8 bv = *reinterpret_cast<const bf16x8*>(&Vt[(ct * 16 + lm) * PV + s * 32 + quad * 8]);
      yacc[ct] = __builtin_amdgcn_mfma_f32_16x16x32_bf16(ap, bv, yacc[ct], 0, 0, 0);
    }
  }
  #pragma unroll
  for (int ct = 0; ct < NYT; ++ct)
    #pragma unroll
    for (int g = 0; g < 4; ++g) {
      int row = rt * 16 + quad * 4 + g;
      int d = ct * 16 + lm;
      Yp[((size_t)b * L + row) * DY + hb + d] = f2us(yacc[ct][g] * inv[g]);
    }
}

// ---------- zg interleave (fp32) ----------
__global__ __launch_bounds__(256)
void interleave_kernel(const float* __restrict__ zg, const float* __restrict__ xg,
                       float* __restrict__ z)
{
  int idx = blockIdx.x * 256 + threadIdx.x;
  int c = idx % 768;
  int tok = idx / 768;
  int b = tok / 96, r = tok % 96;
  int n = r / 3, t = r % 3;
  z[idx] = (t == 0) ? zg[((size_t)b * 32 + n) * 768 + c]
                    : xg[((size_t)b * 64 + 2 * n + (t - 1)) * 768 + c];
}

// ---------- final gather (fp32) ----------
__global__ __launch_bounds__(256)
void gather_kernel(const float* __restrict__ zfin, float* __restrict__ dst)
{
  int idx = blockIdx.x * 256 + threadIdx.x;
  int c = idx % 768;
  int t = (idx / 768) % 64;
  int b = idx / (768 * 64);
  int n = t >> 1, s = t & 1;
  dst[idx] = zfin[((size_t)b * 96 + 3 * n + 1 + s) * 768 + c];
}

extern "C" void kernel_launch(void* const* d_in, const int* in_sizes, int n_in,
                              void* d_out, int out_size, void* d_ws, size_t ws_size,
                              hipStream_t stream) {
  const float* xl = (const float*)d_in[0];
  const float* xg = (const float*)d_in[1];
  const float* l_ln1_w = (const float*)d_in[2];  const float* l_ln1_b = (const float*)d_in[3];
  const float* l_ln2_w = (const float*)d_in[4];  const float* l_ln2_b = (const float*)d_in[5];
  const float* l_wq = (const float*)d_in[6];     const float* l_bq = (const float*)d_in[7];
  const float* l_wk = (const float*)d_in[8];     const float* l_bk = (const float*)d_in[9];
  const float* l_wv = (const float*)d_in[10];    const float* l_bv = (const float*)d_in[11];
  const float* l_wo = (const float*)d_in[12];    const float* l_bo = (const float*)d_in[13];
  const float* l_w1 = (const float*)d_in[14];    const float* l_b1 = (const float*)d_in[15];
  const float* l_w2 = (const float*)d_in[16];    const float* l_b2 = (const float*)d_in[17];
  const float* g_ln1_w = (const float*)d_in[18]; const float* g_ln1_b = (const float*)d_in[19];
  const float* g_ln2_w = (const float*)d_in[20]; const float* g_ln2_b = (const float*)d_in[21];
  const float* g_wq = (const float*)d_in[22];    const float* g_bq = (const float*)d_in[23];
  const float* g_wk = (const float*)d_in[24];    const float* g_bk = (const float*)d_in[25];
  const float* g_wv = (const float*)d_in[26];    const float* g_bv = (const float*)d_in[27];
  const float* g_wo = (const float*)d_in[28];    const float* g_bo = (const float*)d_in[29];
  const float* g_w1 = (const float*)d_in[30];    const float* g_b1 = (const float*)d_in[31];
  const float* g_w2 = (const float*)d_in[32];    const float* g_b2 = (const float*)d_in[33];
  const float* dw   = (const float*)d_in[34];    const float* db   = (const float*)d_in[35];

  float* outL = (float*)d_out;
  float* outG = outL + 12582912;

  char* W = (char*)d_ws;
  ushort* A_bf   = (ushort*)(W + 0);
  ushort* QKVl   = (ushort*)(W + 25165824);
  ushort* XLb    = (ushort*)(W + 75497472);
  float*  X1     = (float*)(W + 100663296);
  ushort* wqkv_t = (ushort*)(W + 150994944);
  ushort* wo_t   = (ushort*)(W + 151216128);
  ushort* w1_t   = (ushort*)(W + 151289856);
  ushort* w2_t   = (ushort*)(W + 151584768);
  ushort* wd_t   = (ushort*)(W + 151879680);
  ushort* wgqkv_t= (ushort*)(W + 170754048);
  ushort* wgo_t  = (ushort*)(W + 174292992);
  ushort* wg1_t  = (ushort*)(W + 175472640);
  ushort* wg2_t  = (ushort*)(W + 180191232);
  float*  bqkv_l = (float*)(W + 184909824);
  float*  bqkv_g = (float*)(W + 184912128);
  // global-phase overlays
  float*  ZGP  = (float*)(W + 0);              // zg partials [8][1024*768]
  float*  FC2P = (float*)(W + 0);              // fc2 partials [4][3072*768] (after Z dead)
  float*  ZG   = (float*)(W + 25165824);
  float*  Z    = (float*)(W + 28311552);
  ushort* LNG  = (ushort*)(W + 37748736);
  ushort* QKVg = (ushort*)(W + 42467328);
  ushort* YG   = (ushort*)(W + 56623104);
  float*  X1G  = (float*)(W + 61341696);
  ushort* HLNG = (ushort*)(W + 70778880);
  ushort* HIDg = (ushort*)(W + 100663296);
  float*  OUTG = (float*)(W + 119537664);

  // ---- weight conversion (1 launch) + bias packs ----
  TJobs tj;
  tj.s[0] = l_wq; tj.s[1] = l_wk; tj.s[2] = l_wv; tj.s[3] = l_wo;
  tj.s[4] = l_w1; tj.s[5] = l_w2; tj.s[6] = dw;
  tj.s[7] = g_wq; tj.s[8] = g_wk; tj.s[9] = g_wv; tj.s[10] = g_wo;
  tj.s[11] = g_w1; tj.s[12] = g_w2;
  tj.d[0] = wqkv_t; tj.d[1] = wqkv_t; tj.d[2] = wqkv_t; tj.d[3] = wo_t;
  tj.d[4] = w1_t; tj.d[5] = w2_t; tj.d[6] = wd_t;
  tj.d[7] = wgqkv_t; tj.d[8] = wgqkv_t; tj.d[9] = wgqkv_t; tj.d[10] = wgo_t;
  tj.d[11] = wg1_t; tj.d[12] = wg2_t;
  transp_all<<<4140, 256, 0, stream>>>(tj);
  pack3_kernel<<<3, 256, 0, stream>>>(bqkv_l, l_bq, 192, l_bk, 192, l_bv, 192);
  pack3_kernel<<<9, 256, 0, stream>>>(bqkv_g, g_bq, 768, g_bk, 768, g_bv, 768);

  // ---- local block ----
  ln_kernel<192><<<16384, 256, 0, stream>>>(xl, l_ln1_w, l_ln1_b, A_bf, 65536);
  mgemm<0,0,0,1,1><<<dim3(9,512), 256, 0, stream>>>(A_bf, wqkv_t, bqkv_l, nullptr, nullptr, QKVl, 65536, 576, 192);
  fattn<64,32,4><<<6144, 256, 0, stream>>>(QKVl, A_bf, 6, 576, 192, 0, 192, 384);
  mgemm<0,1,1,0,1><<<dim3(3,512), 256, 0, stream>>>(A_bf, wo_t, l_bo, xl, X1, nullptr, 65536, 192, 192);
  ln_kernel<192><<<16384, 256, 0, stream>>>(X1, l_ln2_w, l_ln2_b, A_bf, 65536);
  fused_mlp<<<1024, 256, 0, stream>>>(A_bf, w1_t, w2_t, l_b1, l_b2, X1, outL, XLb);
  // ---- group summary projection (128-tile, split-K=8) + interleave ----
  mgemm128<0,0,1,0,0,1><<<dim3(6,8,8), 256, 0, stream>>>(XLb, wd_t, nullptr, nullptr, ZGP, nullptr, 1024, 768, 12288, 1536);
  reduce8_kernel<<<3072, 256, 0, stream>>>(ZGP, db, ZG);
  interleave_kernel<<<9216, 256, 0, stream>>>(ZG, xg, Z);
  // ---- global block ----
  ln_kernel<768><<<768, 256, 0, stream>>>(Z, g_ln1_w, g_ln1_b, LNG, 3072);
  mgemm128<0,0,0,1,1,0><<<dim3(18,24), 256, 0, stream>>>(LNG, wgqkv_t, bqkv_g, nullptr, nullptr, QKVg, 3072, 2304, 768, 0);
  fattn<96,64,6><<<384, 384, 0, stream>>>(QKVg, YG, 12, 2304, 768, 0, 768, 1536);
  mgemm<0,1,1,0,1><<<dim3(12,24), 256, 0, stream>>>(YG, wgo_t, g_bo, Z, X1G, nullptr, 3072, 768, 768);
  ln_kernel<768><<<768, 256, 0, stream>>>(X1G, g_ln2_w, g_ln2_b, HLNG, 3072);
  mgemm128<1,0,0,1,1,0><<<dim3(24,24), 256, 0, stream>>>(HLNG, wg1_t, g_b1, nullptr, nullptr, HIDg, 3072, 3072, 768, 0);
  mgemm128<0,0,1,0,0,1><<<dim3(6,24,4), 256, 0, stream>>>(HIDg, wg2_t, nullptr, nullptr, FC2P, nullptr, 3072, 768, 3072, 768);
  reduce4res_kernel<<<9216, 256, 0, stream>>>(FC2P, g_b2, X1G, OUTG);
  gather_kernel<<<6144, 256, 0, stream>>>(OUTG, outG);
}

// Round 6
// 696.412 us; speedup vs baseline: 1.0777x; 1.0038x over previous
//
#include <hip/hip_runtime.h>
#include <hip/hip_bf16.h>

// StARformer round 9: fused_mlp v3 — one-barrier structure. v2's counters
// (684 GB/s, MfmaUtil 9%, VALU 15.6%) showed latency-bound: 24 syncthreads
// per block each drained vmcnt(0) around just-in-time weight loads. v3:
// 32 rows/block, FULL hid row-block (32x768) in LDS; phase A (12 independent
// col-tiles/wave, no barriers) -> ONE syncthreads -> phase B (single K=768
// GEMM, 24 independent unrolled K-steps). Nothing carried across the barrier
// in registers (r6/r7 scratch lesson). 49.7 KB LDS -> 3 blocks/CU.

typedef unsigned short ushort;
typedef __bf16 bf16x8 __attribute__((ext_vector_type(8)));
typedef float f32x4 __attribute__((ext_vector_type(4)));

__device__ __forceinline__ ushort f2us(float f) {
  __hip_bfloat16 h = __float2bfloat16(f);
  return *reinterpret_cast<ushort*>(&h);
}
__device__ __forceinline__ float gelu_exact(float v) {
  return 0.5f * v * (1.f + erff(v * 0.70710678118654752f));
}
__device__ __forceinline__ void gload16(const ushort* g, ushort* l) {
  __builtin_amdgcn_global_load_lds(
      (const __attribute__((address_space(1))) void*)g,
      (__attribute__((address_space(3))) void*)l, 16, 0, 0);
}

// ---------- batched transpose+convert: 13 weight jobs in one launch ----------
struct TJobs { const float* s[13]; ushort* d[13]; };

__global__ __launch_bounds__(256)
void transp_all(TJobs J)
{
  static constexpr int NN[13]  = {192,192,192,192,768,192,768,768,768,768,768,3072,768};
  static constexpr int SS[13]  = {192,192,192,192,192,768,12288,768,768,768,768,768,3072};
  static constexpr int RO[13]  = {0,192,384,0,0,0,0,0,768,1536,0,0,0};
  static constexpr int CUM[14] = {0,9,18,27,36,72,108,2412,2556,2700,2844,2988,3564,4140};
  __shared__ float t[64][65];
  int bid = blockIdx.x;
  int j = 0;
  while (bid >= CUM[j + 1]) ++j;
  int tIdx = bid - CUM[j];
  const int N = NN[j], stride = SS[j], rowOff = RO[j];
  const int nx = N >> 6;
  const int n0 = (tIdx % nx) * 64, k0 = (tIdx / nx) * 64;
  const float* W = J.s[j];
  ushort* Wt = J.d[j];
  int c = threadIdx.x & 63, r = threadIdx.x >> 6;
  #pragma unroll
  for (int i = 0; i < 16; ++i) {
    int kr = r + i * 4;
    t[kr][c] = W[(size_t)(k0 + kr) * N + n0 + c];
  }
  __syncthreads();
  #pragma unroll
  for (int i = 0; i < 16; ++i) {
    int nr = r + i * 4;
    Wt[(size_t)(rowOff + n0 + nr) * stride + k0 + c] = f2us(t[c][nr]);
  }
}

// ---------- pack 3 bias vectors ----------
__global__ __launch_bounds__(256)
void pack3_kernel(float* dst, const float* a, int na, const float* b, int nb,
                  const float* c, int nc)
{
  int i = blockIdx.x * 256 + threadIdx.x;
  if (i >= na + nb + nc) return;
  dst[i] = (i < na) ? a[i] : (i < na + nb ? b[i - na] : c[i - na - nb]);
}

// ---------- LayerNorm: one wave per row, fp32 in, bf16 out ----------
template<int D>
__global__ __launch_bounds__(256)
void ln_kernel(const float* __restrict__ x, const float* __restrict__ g,
               const float* __restrict__ bb, ushort* __restrict__ out, int rows)
{
  int wave = threadIdx.x >> 6, lane = threadIdx.x & 63;
  int row = blockIdx.x * 4 + wave;
  if (row >= rows) return;
  const float* xr = x + (size_t)row * D;
  constexpr int E = D / 64;
  float vals[E];
  float s = 0.f;
  #pragma unroll
  for (int e = 0; e < E; ++e) { vals[e] = xr[e * 64 + lane]; s += vals[e]; }
  #pragma unroll
  for (int off = 32; off >= 1; off >>= 1) s += __shfl_xor(s, off);
  float m = s * (1.f / D);
  float s2 = 0.f;
  #pragma unroll
  for (int e = 0; e < E; ++e) { float d = vals[e] - m; s2 += d * d; }
  #pragma unroll
  for (int off = 32; off >= 1; off >>= 1) s2 += __shfl_xor(s2, off);
  float rstd = rsqrtf(s2 * (1.f / D) + 1e-5f);
  ushort* orow = out + (size_t)row * D;
  #pragma unroll
  for (int e = 0; e < E; ++e) {
    int c = e * 64 + lane;
    orow[c] = f2us((vals[e] - m) * rstd * g[c] + bb[c]);
  }
}

// ---------- fused local MLP v3: out = res + b2 + gelu(A@w1 + b1) @ w2 ----------
// 32 rows/block. Phase A: full hid[32][768] -> LDS (12 col-tiles/wave, no
// barriers). ONE syncthreads. Phase B: out[32][192] = hid @ w2, K=768.
__global__ __launch_bounds__(256, 2)
void fused_mlp(const ushort* __restrict__ A, const ushort* __restrict__ W1t,
               const ushort* __restrict__ W2t, const float* __restrict__ b1,
               const float* __restrict__ b2, const float* __restrict__ resF,
               float* __restrict__ Cf, ushort* __restrict__ Cb)
{
  constexpr int PH = 776;                        // 768 + 8 pad
  __shared__ __align__(16) ushort Hsf[32 * PH];  // full hid row-block, 49.7 KB
  const int tid = threadIdx.x;
  const int wave = tid >> 6, lane = tid & 63;
  const int quad = lane >> 4, lm = lane & 15;
  const int rowBase = blockIdx.x * 32;

  // ---- phase A: hid[32][768] = gelu(A @ w1 + b1); wave w owns cols [w*192,..)
  {
    // A fragments: 2 row-tiles x 6 k-tiles (same for all waves; L2 broadcast)
    bf16x8 afr[2][6];
    #pragma unroll
    for (int r2 = 0; r2 < 2; ++r2)
      #pragma unroll
      for (int kt = 0; kt < 6; ++kt)
        afr[r2][kt] = *reinterpret_cast<const bf16x8*>(
            &A[(size_t)(rowBase + r2 * 16 + lm) * 192 + kt * 32 + quad * 8]);

    const int cb = wave * 192;
    #pragma unroll
    for (int ct = 0; ct < 12; ++ct) {
      const int col = cb + ct * 16 + lm;
      f32x4 acc1[2] = {};
      #pragma unroll
      for (int kt = 0; kt < 6; ++kt) {
        bf16x8 bfr = *reinterpret_cast<const bf16x8*>(
            &W1t[(size_t)col * 192 + kt * 32 + quad * 8]);
        #pragma unroll
        for (int r2 = 0; r2 < 2; ++r2)
          acc1[r2] = __builtin_amdgcn_mfma_f32_16x16x32_bf16(
              afr[r2][kt], bfr, acc1[r2], 0, 0, 0);
      }
      float bb1 = b1[col];
      #pragma unroll
      for (int r2 = 0; r2 < 2; ++r2)
        #pragma unroll
        for (int g = 0; g < 4; ++g) {
          int row = r2 * 16 + quad * 4 + g;
          Hsf[row * PH + col] = f2us(gelu_exact(acc1[r2][g] + bb1));
        }
    }
  }
  __syncthreads();   // the ONLY barrier

  // ---- phase B: out[32][192] = hid @ w2; wave w owns out-cols [w*48, w*48+48)
  const int ob = wave * 48;
  f32x4 acc2[2][3] = {};
  #pragma unroll
  for (int ks = 0; ks < 24; ++ks) {
    bf16x8 ap[2], bp[3];
    #pragma unroll
    for (int r2 = 0; r2 < 2; ++r2)
      ap[r2] = *reinterpret_cast<const bf16x8*>(
          &Hsf[(r2 * 16 + lm) * PH + ks * 32 + quad * 8]);
    #pragma unroll
    for (int c2 = 0; c2 < 3; ++c2)
      bp[c2] = *reinterpret_cast<const bf16x8*>(
          &W2t[(size_t)(ob + c2 * 16 + lm) * 768 + ks * 32 + quad * 8]);
    #pragma unroll
    for (int r2 = 0; r2 < 2; ++r2)
      #pragma unroll
      for (int c2 = 0; c2 < 3; ++c2)
        acc2[r2][c2] = __builtin_amdgcn_mfma_f32_16x16x32_bf16(
            ap[r2], bp[c2], acc2[r2][c2], 0, 0, 0);
  }
  // ---- epilogue: + b2 + residual, write fp32 + bf16
  #pragma unroll
  for (int r2 = 0; r2 < 2; ++r2)
    #pragma unroll
    for (int c2 = 0; c2 < 3; ++c2) {
      int col = ob + c2 * 16 + lm;
      float bb2 = b2[col];
      #pragma unroll
      for (int g = 0; g < 4; ++g) {
        int row = rowBase + r2 * 16 + quad * 4 + g;
        size_t idx = (size_t)row * 192 + col;
        float v = acc2[r2][c2][g] + bb2 + resF[idx];
        Cf[idx] = v;
        Cb[idx] = f2us(v);
      }
    }
}

// ---------- MFMA GEMM 128x64: BM=128 BN=64 BK=32, 4 waves (2x2) ----------
// Depth-2 pipelined: raw s_barrier, counted vmcnt(3) steady state.
template<int ACT, int RES, int OUTF, int OUTB, int BIAS>
__global__ __launch_bounds__(256)
void mgemm(const ushort* __restrict__ A, const ushort* __restrict__ Bt,
           const float* __restrict__ bias, const float* __restrict__ resF,
           float* __restrict__ Cf, ushort* __restrict__ Cb,
           int M, int N, int K)
{
  __shared__ __align__(16) ushort Asm[2][128 * 32];
  __shared__ __align__(16) ushort Bsm[2][64 * 32];
  const int tid = threadIdx.x;
  const int wave = tid >> 6, lane = tid & 63;
  const int quad = lane >> 4, lm = lane & 15;
  const int rowBase = blockIdx.y * 128, colBase = blockIdx.x * 64;
  const int wrow = (wave & 1) * 64, wcol = (wave >> 1) * 32;
  const int srow = lane >> 2, skcol = (lane & 3) * 8;
  const int nIter = K >> 5;

  auto stage = [&](int buf, int it) {
    const int k0 = it * 32;
    #pragma unroll
    for (int uu = 0; uu < 3; ++uu) {
      const int u = wave * 3 + uu;
      if (u < 8) {
        const ushort* gp = A + (size_t)(rowBase + u * 16 + srow) * K + k0 + skcol;
        gload16(gp, &Asm[buf][u * 512]);
      } else {
        const int v = u - 8;
        const ushort* gp = Bt + (size_t)(colBase + v * 16 + srow) * K + k0 + skcol;
        gload16(gp, &Bsm[buf][v * 512]);
      }
    }
  };

  f32x4 acc[4][2] = {};
  stage(0, 0);
  if (nIter > 1) stage(1, 1);

  for (int t = 0; t < nIter; ++t) {
    const int cur = t & 1;
    if (t + 1 < nIter) asm volatile("s_waitcnt vmcnt(3)" ::: "memory");
    else               asm volatile("s_waitcnt vmcnt(0)" ::: "memory");
    __builtin_amdgcn_s_barrier();
    bf16x8 af[4], bfr[2];
    #pragma unroll
    for (int r2 = 0; r2 < 4; ++r2)
      af[r2] = *reinterpret_cast<const bf16x8*>(&Asm[cur][(wrow + r2 * 16 + lm) * 32 + quad * 8]);
    #pragma unroll
    for (int c2 = 0; c2 < 2; ++c2)
      bfr[c2] = *reinterpret_cast<const bf16x8*>(&Bsm[cur][(wcol + c2 * 16 + lm) * 32 + quad * 8]);
    asm volatile("s_waitcnt lgkmcnt(0)" ::: "memory");
    __builtin_amdgcn_s_barrier();
    if (t + 2 < nIter) stage(cur, t + 2);
    #pragma unroll
    for (int r2 = 0; r2 < 4; ++r2)
      #pragma unroll
      for (int c2 = 0; c2 < 2; ++c2)
        acc[r2][c2] = __builtin_amdgcn_mfma_f32_16x16x32_bf16(af[r2], bfr[c2], acc[r2][c2], 0, 0, 0);
  }

  #pragma unroll
  for (int r2 = 0; r2 < 4; ++r2) {
    #pragma unroll
    for (int c2 = 0; c2 < 2; ++c2) {
      int col = colBase + wcol + c2 * 16 + lm;
      int row0 = rowBase + wrow + r2 * 16 + quad * 4;
      #pragma unroll
      for (int g = 0; g < 4; ++g) {
        float v = acc[r2][c2][g];
        size_t idx = (size_t)(row0 + g) * N + col;
        if (BIAS) v += bias[col];
        if (ACT == 1) v = gelu_exact(v);
        if (RES) v += resF[idx];
        if (OUTF) Cf[idx] = v;
        if (OUTB) Cb[idx] = f2us(v);
      }
    }
  }
}

// ---------- MFMA GEMM 128x128: BM=128 BN=128 BK=32, 4 waves each 64x64 ----------
template<int ACT, int RES, int OUTF, int OUTB, int BIAS, int SPLITK>
__global__ __launch_bounds__(256)
void mgemm128(const ushort* __restrict__ A, const ushort* __restrict__ Bt,
              const float* __restrict__ bias, const float* __restrict__ resF,
              float* __restrict__ Cf, ushort* __restrict__ Cb,
              int M, int N, int K, int kChunk)
{
  __shared__ __align__(16) ushort Asm[2][128 * 32];
  __shared__ __align__(16) ushort Bsm[2][128 * 32];
  const int tid = threadIdx.x;
  const int wave = tid >> 6, lane = tid & 63;
  const int quad = lane >> 4, lm = lane & 15;
  const int rowBase = blockIdx.y * 128, colBase = blockIdx.x * 128;
  const int wrow = (wave & 1) * 64, wcol = (wave >> 1) * 64;
  const int srow = lane >> 2, skcol = (lane & 3) * 8;

  const int kbeg = SPLITK ? blockIdx.z * kChunk : 0;
  const int nIter = (SPLITK ? kChunk : K) >> 5;

  auto stage = [&](int buf, int it) {
    const int k0 = kbeg + it * 32;
    #pragma unroll
    for (int uu = 0; uu < 4; ++uu) {
      const int u = wave * 4 + uu;
      if (u < 8) {
        const ushort* gp = A + (size_t)(rowBase + u * 16 + srow) * K + k0 + skcol;
        gload16(gp, &Asm[buf][u * 512]);
      } else {
        const int v = u - 8;
        const ushort* gp = Bt + (size_t)(colBase + v * 16 + srow) * K + k0 + skcol;
        gload16(gp, &Bsm[buf][v * 512]);
      }
    }
  };

  f32x4 acc[4][4] = {};
  stage(0, 0);
  if (nIter > 1) stage(1, 1);

  for (int t = 0; t < nIter; ++t) {
    const int cur = t & 1;
    if (t + 1 < nIter) asm volatile("s_waitcnt vmcnt(4)" ::: "memory");
    else               asm volatile("s_waitcnt vmcnt(0)" ::: "memory");
    __builtin_amdgcn_s_barrier();
    bf16x8 af[4], bfr[4];
    #pragma unroll
    for (int r2 = 0; r2 < 4; ++r2)
      af[r2] = *reinterpret_cast<const bf16x8*>(&Asm[cur][(wrow + r2 * 16 + lm) * 32 + quad * 8]);
    #pragma unroll
    for (int c2 = 0; c2 < 4; ++c2)
      bfr[c2] = *reinterpret_cast<const bf16x8*>(&Bsm[cur][(wcol + c2 * 16 + lm) * 32 + quad * 8]);
    asm volatile("s_waitcnt lgkmcnt(0)" ::: "memory");
    __builtin_amdgcn_s_barrier();
    if (t + 2 < nIter) stage(cur, t + 2);
    #pragma unroll
    for (int r2 = 0; r2 < 4; ++r2)
      #pragma unroll
      for (int c2 = 0; c2 < 4; ++c2)
        acc[r2][c2] = __builtin_amdgcn_mfma_f32_16x16x32_bf16(af[r2], bfr[c2], acc[r2][c2], 0, 0, 0);
  }

  const size_t zoff = SPLITK ? (size_t)blockIdx.z * M * N : 0;
  #pragma unroll
  for (int r2 = 0; r2 < 4; ++r2) {
    #pragma unroll
    for (int c2 = 0; c2 < 4; ++c2) {
      int col = colBase + wcol + c2 * 16 + lm;
      int row0 = rowBase + wrow + r2 * 16 + quad * 4;
      #pragma unroll
      for (int g = 0; g < 4; ++g) {
        float v = acc[r2][c2][g];
        size_t idx = (size_t)(row0 + g) * N + col;
        if (BIAS) v += bias[col];
        if (ACT == 1) v = gelu_exact(v);
        if (RES) v += resF[idx];
        if (OUTF) Cf[zoff + idx] = v;
        if (OUTB) Cb[idx] = f2us(v);
      }
    }
  }
}

// ---------- split-K reduce for zg: ZG = sum_8 P + bias ----------
__global__ __launch_bounds__(256)
void reduce8_kernel(const float* __restrict__ P, const float* __restrict__ db,
                    float* __restrict__ ZG)
{
  int i = blockIdx.x * 256 + threadIdx.x;
  float s = db[i % 768];
  #pragma unroll
  for (int k = 0; k < 8; ++k) s += P[i + k * 786432];
  ZG[i] = s;
}

// ---------- split-K reduce for global fc2: out = sum_4 P + bias + res ----------
__global__ __launch_bounds__(256)
void reduce4res_kernel(const float* __restrict__ P, const float* __restrict__ db,
                       const float* __restrict__ res, float* __restrict__ out)
{
  int i = blockIdx.x * 256 + threadIdx.x;   // 3072*768
  float s = db[i % 768] + res[i];
  #pragma unroll
  for (int k = 0; k < 4; ++k) s += P[i + k * 2359296];
  out[i] = s;
}

// ---------- MFMA fused attention: one block per (seq, head), causal ----------
template<int L, int HD, int NW>
__global__ __launch_bounds__(NW * 64)
void fattn(const ushort* __restrict__ QKV, ushort* __restrict__ Yp,
           int nh, int DS, int DY, int offQ, int offK, int offV)
{
  constexpr int PQ = HD + 8;
  constexpr int PV = L + 8;
  constexpr int KS = HD / 32;
  constexpr int NCT = L / 16;
  constexpr int KS2 = L / 32;
  constexpr int NYT = HD / 16;
  constexpr int T = NW * 64;
  __shared__ __align__(16) ushort Ql[L * PQ];
  __shared__ __align__(16) ushort Kl[L * PQ];
  __shared__ __align__(16) ushort Vt[HD * PV];
  __shared__ __align__(16) ushort Ps[L * PV];
  const int tid = threadIdx.x;
  const int b = blockIdx.x / nh, h = blockIdx.x % nh;
  const size_t rowb = (size_t)b * L * DS;
  const int hb = h * HD;
  constexpr int CH = L * HD / 8;
  for (int idx = tid; idx < CH; idx += T) {
    int row = idx / (HD / 8), seg = idx % (HD / 8);
    uint4 q4 = *reinterpret_cast<const uint4*>(&QKV[rowb + (size_t)row * DS + offQ + hb + seg * 8]);
    *reinterpret_cast<uint4*>(&Ql[row * PQ + seg * 8]) = q4;
    uint4 k4 = *reinterpret_cast<const uint4*>(&QKV[rowb + (size_t)row * DS + offK + hb + seg * 8]);
    *reinterpret_cast<uint4*>(&Kl[row * PQ + seg * 8]) = k4;
  }
  for (int idx = tid; idx < L * HD; idx += T) {
    int j = idx / HD, d = idx % HD;
    Vt[d * PV + j] = QKV[rowb + (size_t)j * DS + offV + hb + d];
  }
  __syncthreads();
  const int lane = tid & 63;
  const int quad = lane >> 4, lm = lane & 15;
  const int rt = tid >> 6;
  const float scale = rsqrtf((float)HD);
  bf16x8 af[KS];
  #pragma unroll
  for (int s = 0; s < KS; ++s)
    af[s] = *reinterpret_cast<const bf16x8*>(&Ql[(rt * 16 + lm) * PQ + s * 32 + quad * 8]);
  f32x4 sacc[NCT] = {};
  #pragma unroll
  for (int ct = 0; ct < NCT; ++ct)
    #pragma unroll
    for (int s = 0; s < KS; ++s) {
      bf16x8 bf = *reinterpret_cast<const bf16x8*>(&Kl[(ct * 16 + lm) * PQ + s * 32 + quad * 8]);
      sacc[ct] = __builtin_amdgcn_mfma_f32_16x16x32_bf16(af[s], bf, sacc[ct], 0, 0, 0);
    }
  float inv[4];
  #pragma unroll
  for (int g = 0; g < 4; ++g) {
    const int row = rt * 16 + quad * 4 + g;
    float sv[NCT]; float m = -1e30f;
    #pragma unroll
    for (int ct = 0; ct < NCT; ++ct) {
      int col = ct * 16 + lm;
      float x = sacc[ct][g] * scale;
      sv[ct] = (col <= row) ? x : -1e30f;
      m = fmaxf(m, sv[ct]);
    }
    #pragma unroll
    for (int off = 8; off >= 1; off >>= 1) m = fmaxf(m, __shfl_xor(m, off));
    float l = 0.f;
    #pragma unroll
    for (int ct = 0; ct < NCT; ++ct) {
      float p = __expf(sv[ct] - m);
      l += p;
      Ps[row * PV + ct * 16 + lm] = f2us(p);
    }
    #pragma unroll
    for (int off = 8; off >= 1; off >>= 1) l += __shfl_xor(l, off);
    inv[g] = 1.f / l;
  }
  __syncthreads();
  f32x4 yacc[NYT] = {};
  #pragma unroll
  for (int s = 0; s < KS2; ++s) {
    bf16x8 ap = *reinterpret_cast<const bf16x8*>(&Ps[(rt * 16 + lm) * PV + s * 32 + quad * 8]);
    #pragma unroll
    for (int ct = 0; ct < NYT; ++ct) {
      bf16x8 bv = *reinterpret_cast<const bf16x8*>(&Vt[(ct * 16 + lm) * PV + s * 32 + quad * 8]);
      yacc[ct] = __builtin_amdgcn_mfma_f32_16x16x32_bf16(ap, bv, yacc[ct], 0, 0, 0);
    }
  }
  #pragma unroll
  for (int ct = 0; ct < NYT; ++ct)
    #pragma unroll
    for (int g = 0; g < 4; ++g) {
      int row = rt * 16 + quad * 4 + g;
      int d = ct * 16 + lm;
      Yp[((size_t)b * L + row) * DY + hb + d] = f2us(yacc[ct][g] * inv[g]);
    }
}

// ---------- zg interleave (fp32) ----------
__global__ __launch_bounds__(256)
void interleave_kernel(const float* __restrict__ zg, const float* __restrict__ xg,
                       float* __restrict__ z)
{
  int idx = blockIdx.x * 256 + threadIdx.x;
  int c = idx % 768;
  int tok = idx / 768;
  int b = tok / 96, r = tok % 96;
  int n = r / 3, t = r % 3;
  z[idx] = (t == 0) ? zg[((size_t)b * 32 + n) * 768 + c]
                    : xg[((size_t)b * 64 + 2 * n + (t - 1)) * 768 + c];
}

// ---------- final gather (fp32) ----------
__global__ __launch_bounds__(256)
void gather_kernel(const float* __restrict__ zfin, float* __restrict__ dst)
{
  int idx = blockIdx.x * 256 + threadIdx.x;
  int c = idx % 768;
  int t = (idx / 768) % 64;
  int b = idx / (768 * 64);
  int n = t >> 1, s = t & 1;
  dst[idx] = zfin[((size_t)b * 96 + 3 * n + 1 + s) * 768 + c];
}

extern "C" void kernel_launch(void* const* d_in, const int* in_sizes, int n_in,
                              void* d_out, int out_size, void* d_ws, size_t ws_size,
                              hipStream_t stream) {
  const float* xl = (const float*)d_in[0];
  const float* xg = (const float*)d_in[1];
  const float* l_ln1_w = (const float*)d_in[2];  const float* l_ln1_b = (const float*)d_in[3];
  const float* l_ln2_w = (const float*)d_in[4];  const float* l_ln2_b = (const float*)d_in[5];
  const float* l_wq = (const float*)d_in[6];     const float* l_bq = (const float*)d_in[7];
  const float* l_wk = (const float*)d_in[8];     const float* l_bk = (const float*)d_in[9];
  const float* l_wv = (const float*)d_in[10];    const float* l_bv = (const float*)d_in[11];
  const float* l_wo = (const float*)d_in[12];    const float* l_bo = (const float*)d_in[13];
  const float* l_w1 = (const float*)d_in[14];    const float* l_b1 = (const float*)d_in[15];
  const float* l_w2 = (const float*)d_in[16];    const float* l_b2 = (const float*)d_in[17];
  const float* g_ln1_w = (const float*)d_in[18]; const float* g_ln1_b = (const float*)d_in[19];
  const float* g_ln2_w = (const float*)d_in[20]; const float* g_ln2_b = (const float*)d_in[21];
  const float* g_wq = (const float*)d_in[22];    const float* g_bq = (const float*)d_in[23];
  const float* g_wk = (const float*)d_in[24];    const float* g_bk = (const float*)d_in[25];
  const float* g_wv = (const float*)d_in[26];    const float* g_bv = (const float*)d_in[27];
  const float* g_wo = (const float*)d_in[28];    const float* g_bo = (const float*)d_in[29];
  const float* g_w1 = (const float*)d_in[30];    const float* g_b1 = (const float*)d_in[31];
  const float* g_w2 = (const float*)d_in[32];    const float* g_b2 = (const float*)d_in[33];
  const float* dw   = (const float*)d_in[34];    const float* db   = (const float*)d_in[35];

  float* outL = (float*)d_out;
  float* outG = outL + 12582912;

  char* W = (char*)d_ws;
  ushort* A_bf   = (ushort*)(W + 0);
  ushort* QKVl   = (ushort*)(W + 25165824);
  ushort* XLb    = (ushort*)(W + 75497472);
  float*  X1     = (float*)(W + 100663296);
  ushort* wqkv_t = (ushort*)(W + 150994944);
  ushort* wo_t   = (ushort*)(W + 151216128);
  ushort* w1_t   = (ushort*)(W + 151289856);
  ushort* w2_t   = (ushort*)(W + 151584768);
  ushort* wd_t   = (ushort*)(W + 151879680);
  ushort* wgqkv_t= (ushort*)(W + 170754048);
  ushort* wgo_t  = (ushort*)(W + 174292992);
  ushort* wg1_t  = (ushort*)(W + 175472640);
  ushort* wg2_t  = (ushort*)(W + 180191232);
  float*  bqkv_l = (float*)(W + 184909824);
  float*  bqkv_g = (float*)(W + 184912128);
  // global-phase overlays
  float*  ZGP  = (float*)(W + 0);              // zg partials [8][1024*768]
  float*  FC2P = (float*)(W + 0);              // fc2 partials [4][3072*768] (after Z dead)
  float*  ZG   = (float*)(W + 25165824);
  float*  Z    = (float*)(W + 28311552);
  ushort* LNG  = (ushort*)(W + 37748736);
  ushort* QKVg = (ushort*)(W + 42467328);
  ushort* YG   = (ushort*)(W + 56623104);
  float*  X1G  = (float*)(W + 61341696);
  ushort* HLNG = (ushort*)(W + 70778880);
  ushort* HIDg = (ushort*)(W + 100663296);
  float*  OUTG = (float*)(W + 119537664);

  // ---- weight conversion (1 launch) + bias packs ----
  TJobs tj;
  tj.s[0] = l_wq; tj.s[1] = l_wk; tj.s[2] = l_wv; tj.s[3] = l_wo;
  tj.s[4] = l_w1; tj.s[5] = l_w2; tj.s[6] = dw;
  tj.s[7] = g_wq; tj.s[8] = g_wk; tj.s[9] = g_wv; tj.s[10] = g_wo;
  tj.s[11] = g_w1; tj.s[12] = g_w2;
  tj.d[0] = wqkv_t; tj.d[1] = wqkv_t; tj.d[2] = wqkv_t; tj.d[3] = wo_t;
  tj.d[4] = w1_t; tj.d[5] = w2_t; tj.d[6] = wd_t;
  tj.d[7] = wgqkv_t; tj.d[8] = wgqkv_t; tj.d[9] = wgqkv_t; tj.d[10] = wgo_t;
  tj.d[11] = wg1_t; tj.d[12] = wg2_t;
  transp_all<<<4140, 256, 0, stream>>>(tj);
  pack3_kernel<<<3, 256, 0, stream>>>(bqkv_l, l_bq, 192, l_bk, 192, l_bv, 192);
  pack3_kernel<<<9, 256, 0, stream>>>(bqkv_g, g_bq, 768, g_bk, 768, g_bv, 768);

  // ---- local block ----
  ln_kernel<192><<<16384, 256, 0, stream>>>(xl, l_ln1_w, l_ln1_b, A_bf, 65536);
  mgemm<0,0,0,1,1><<<dim3(9,512), 256, 0, stream>>>(A_bf, wqkv_t, bqkv_l, nullptr, nullptr, QKVl, 65536, 576, 192);
  fattn<64,32,4><<<6144, 256, 0, stream>>>(QKVl, A_bf, 6, 576, 192, 0, 192, 384);
  mgemm<0,1,1,0,1><<<dim3(3,512), 256, 0, stream>>>(A_bf, wo_t, l_bo, xl, X1, nullptr, 65536, 192, 192);
  ln_kernel<192><<<16384, 256, 0, stream>>>(X1, l_ln2_w, l_ln2_b, A_bf, 65536);
  fused_mlp<<<2048, 256, 0, stream>>>(A_bf, w1_t, w2_t, l_b1, l_b2, X1, outL, XLb);
  // ---- group summary projection (128-tile, split-K=8) + interleave ----
  mgemm128<0,0,1,0,0,1><<<dim3(6,8,8), 256, 0, stream>>>(XLb, wd_t, nullptr, nullptr, ZGP, nullptr, 1024, 768, 12288, 1536);
  reduce8_kernel<<<3072, 256, 0, stream>>>(ZGP, db, ZG);
  interleave_kernel<<<9216, 256, 0, stream>>>(ZG, xg, Z);
  // ---- global block ----
  ln_kernel<768><<<768, 256, 0, stream>>>(Z, g_ln1_w, g_ln1_b, LNG, 3072);
  mgemm128<0,0,0,1,1,0><<<dim3(18,24), 256, 0, stream>>>(LNG, wgqkv_t, bqkv_g, nullptr, nullptr, QKVg, 3072, 2304, 768, 0);
  fattn<96,64,6><<<384, 384, 0, stream>>>(QKVg, YG, 12, 2304, 768, 0, 768, 1536);
  mgemm<0,1,1,0,1><<<dim3(12,24), 256, 0, stream>>>(YG, wgo_t, g_bo, Z, X1G, nullptr, 3072, 768, 768);
  ln_kernel<768><<<768, 256, 0, stream>>>(X1G, g_ln2_w, g_ln2_b, HLNG, 3072);
  mgemm128<1,0,0,1,1,0><<<dim3(24,24), 256, 0, stream>>>(HLNG, wg1_t, g_b1, nullptr, nullptr, HIDg, 3072, 3072, 768, 0);
  mgemm128<0,0,1,0,0,1><<<dim3(6,24,4), 256, 0, stream>>>(HIDg, wg2_t, nullptr, nullptr, FC2P, nullptr, 3072, 768, 3072, 768);
  reduce4res_kernel<<<9216, 256, 0, stream>>>(FC2P, g_b2, X1G, OUTG);
  gather_kernel<<<6144, 256, 0, stream>>>(OUTG, outG);
}

// Round 7
// 643.783 us; speedup vs baseline: 1.1658x; 1.0817x over previous
//
#include <hip/hip_runtime.h>
#include <hip/hip_bf16.h>

// StARformer round 10: fused_mlp v4 — fragment-packed weight layout.
// v2 and v3 hit the same 174 µs floor with idle pipes: the shared cost is
// MFMA fragment loads direct from global, which scatter 64 lanes over 16
// cache lines (stride K*2B) = 16 segments/instruction, ~2500 segments/wave.
// Fix: transp_all emits w1_t/w2_t in fragment-packed layout (each 16x32
// fragment = 512 contiguous ushorts, lane-ordered), so a fragment load is
// base + lane*16B -> one contiguous 1 KB burst. Kernel structure unchanged
// from v3 (one barrier, no staging, no scratch).

typedef unsigned short ushort;
typedef __bf16 bf16x8 __attribute__((ext_vector_type(8)));
typedef float f32x4 __attribute__((ext_vector_type(4)));

__device__ __forceinline__ ushort f2us(float f) {
  __hip_bfloat16 h = __float2bfloat16(f);
  return *reinterpret_cast<ushort*>(&h);
}
__device__ __forceinline__ float gelu_exact(float v) {
  return 0.5f * v * (1.f + erff(v * 0.70710678118654752f));
}
__device__ __forceinline__ void gload16(const ushort* g, ushort* l) {
  __builtin_amdgcn_global_load_lds(
      (const __attribute__((address_space(1))) void*)g,
      (__attribute__((address_space(3))) void*)l, 16, 0, 0);
}

// ---------- batched transpose+convert: 13 weight jobs in one launch ----------
// Jobs 4 (l_w1) and 5 (l_w2) are emitted FRAGMENT-PACKED for fused_mlp:
//   dst[ (n>>4)*(K>>5) + (k>>5) ][ lane=((k>>3)&3)*16 + (n&15) ][ k&7 ]
// (512 ushorts per fragment, lane-major). Others stay row-major [n][K].
struct TJobs { const float* s[13]; ushort* d[13]; };

__global__ __launch_bounds__(256)
void transp_all(TJobs J)
{
  static constexpr int NN[13]  = {192,192,192,192,768,192,768,768,768,768,768,3072,768};
  static constexpr int SS[13]  = {192,192,192,192,192,768,12288,768,768,768,768,768,3072};
  static constexpr int RO[13]  = {0,192,384,0,0,0,0,0,768,1536,0,0,0};
  static constexpr int FR[13]  = {0,0,0,0,1,1,0,0,0,0,0,0,0};
  static constexpr int CUM[14] = {0,9,18,27,36,72,108,2412,2556,2700,2844,2988,3564,4140};
  __shared__ float t[64][65];
  int bid = blockIdx.x;
  int j = 0;
  while (bid >= CUM[j + 1]) ++j;
  int tIdx = bid - CUM[j];
  const int N = NN[j], stride = SS[j], rowOff = RO[j];
  const int nx = N >> 6;
  const int n0 = (tIdx % nx) * 64, k0 = (tIdx / nx) * 64;
  const float* W = J.s[j];
  ushort* Wt = J.d[j];
  int c = threadIdx.x & 63, r = threadIdx.x >> 6;
  #pragma unroll
  for (int i = 0; i < 16; ++i) {
    int kr = r + i * 4;
    t[kr][c] = W[(size_t)(k0 + kr) * N + n0 + c];
  }
  __syncthreads();
  if (FR[j]) {
    #pragma unroll
    for (int i = 0; i < 16; ++i) {
      int n = n0 + r + i * 4;      // dst row (rowOff=0 for frag jobs)
      int k = k0 + c;              // dst col
      size_t fi = ((size_t)(n >> 4) * (stride >> 5) + (k >> 5)) * 512
                + (((k >> 3) & 3) * 16 + (n & 15)) * 8 + (k & 7);
      Wt[fi] = f2us(t[c][r + i * 4]);
    }
  } else {
    #pragma unroll
    for (int i = 0; i < 16; ++i) {
      int nr = r + i * 4;
      Wt[(size_t)(rowOff + n0 + nr) * stride + k0 + c] = f2us(t[c][nr]);
    }
  }
}

// ---------- pack 3 bias vectors ----------
__global__ __launch_bounds__(256)
void pack3_kernel(float* dst, const float* a, int na, const float* b, int nb,
                  const float* c, int nc)
{
  int i = blockIdx.x * 256 + threadIdx.x;
  if (i >= na + nb + nc) return;
  dst[i] = (i < na) ? a[i] : (i < na + nb ? b[i - na] : c[i - na - nb]);
}

// ---------- LayerNorm: one wave per row, fp32 in, bf16 out ----------
template<int D>
__global__ __launch_bounds__(256)
void ln_kernel(const float* __restrict__ x, const float* __restrict__ g,
               const float* __restrict__ bb, ushort* __restrict__ out, int rows)
{
  int wave = threadIdx.x >> 6, lane = threadIdx.x & 63;
  int row = blockIdx.x * 4 + wave;
  if (row >= rows) return;
  const float* xr = x + (size_t)row * D;
  constexpr int E = D / 64;
  float vals[E];
  float s = 0.f;
  #pragma unroll
  for (int e = 0; e < E; ++e) { vals[e] = xr[e * 64 + lane]; s += vals[e]; }
  #pragma unroll
  for (int off = 32; off >= 1; off >>= 1) s += __shfl_xor(s, off);
  float m = s * (1.f / D);
  float s2 = 0.f;
  #pragma unroll
  for (int e = 0; e < E; ++e) { float d = vals[e] - m; s2 += d * d; }
  #pragma unroll
  for (int off = 32; off >= 1; off >>= 1) s2 += __shfl_xor(s2, off);
  float rstd = rsqrtf(s2 * (1.f / D) + 1e-5f);
  ushort* orow = out + (size_t)row * D;
  #pragma unroll
  for (int e = 0; e < E; ++e) {
    int c = e * 64 + lane;
    orow[c] = f2us((vals[e] - m) * rstd * g[c] + bb[c]);
  }
}

// ---------- fused local MLP v4: out = res + b2 + gelu(A@w1 + b1) @ w2 ----------
// 32 rows/block, one barrier. W1/W2 fragments loaded from fragment-packed
// layout: frag*512 + lane*8 (contiguous 1 KB per wave load).
__global__ __launch_bounds__(256, 2)
void fused_mlp(const ushort* __restrict__ A, const ushort* __restrict__ W1t,
               const ushort* __restrict__ W2t, const float* __restrict__ b1,
               const float* __restrict__ b2, const float* __restrict__ resF,
               float* __restrict__ Cf, ushort* __restrict__ Cb)
{
  constexpr int PH = 776;                        // 768 + 8 pad
  __shared__ __align__(16) ushort Hsf[32 * PH];  // full hid row-block, 49.7 KB
  const int tid = threadIdx.x;
  const int wave = tid >> 6, lane = tid & 63;
  const int quad = lane >> 4, lm = lane & 15;
  const int rowBase = blockIdx.x * 32;

  // ---- phase A: hid[32][768] = gelu(A @ w1 + b1); wave w owns cols [w*192,..)
  {
    bf16x8 afr[2][6];
    #pragma unroll
    for (int r2 = 0; r2 < 2; ++r2)
      #pragma unroll
      for (int kt = 0; kt < 6; ++kt)
        afr[r2][kt] = *reinterpret_cast<const bf16x8*>(
            &A[(size_t)(rowBase + r2 * 16 + lm) * 192 + kt * 32 + quad * 8]);

    const int cb = wave * 192;
    #pragma unroll
    for (int ct = 0; ct < 12; ++ct) {
      const int col = cb + ct * 16 + lm;
      f32x4 acc1[2] = {};
      #pragma unroll
      for (int kt = 0; kt < 6; ++kt) {
        // fragment (nf = wave*12+ct, kf = kt): contiguous lane-packed
        bf16x8 bfr = *reinterpret_cast<const bf16x8*>(
            &W1t[(size_t)((wave * 12 + ct) * 6 + kt) * 512 + lane * 8]);
        #pragma unroll
        for (int r2 = 0; r2 < 2; ++r2)
          acc1[r2] = __builtin_amdgcn_mfma_f32_16x16x32_bf16(
              afr[r2][kt], bfr, acc1[r2], 0, 0, 0);
      }
      float bb1 = b1[col];
      #pragma unroll
      for (int r2 = 0; r2 < 2; ++r2)
        #pragma unroll
        for (int g = 0; g < 4; ++g) {
          int row = r2 * 16 + quad * 4 + g;
          Hsf[row * PH + col] = f2us(gelu_exact(acc1[r2][g] + bb1));
        }
    }
  }
  __syncthreads();   // the ONLY barrier

  // ---- phase B: out[32][192] = hid @ w2; wave w owns out-cols [w*48, w*48+48)
  const int ob = wave * 48;
  f32x4 acc2[2][3] = {};
  #pragma unroll
  for (int ks = 0; ks < 24; ++ks) {
    bf16x8 ap[2], bp[3];
    #pragma unroll
    for (int r2 = 0; r2 < 2; ++r2)
      ap[r2] = *reinterpret_cast<const bf16x8*>(
          &Hsf[(r2 * 16 + lm) * PH + ks * 32 + quad * 8]);
    #pragma unroll
    for (int c2 = 0; c2 < 3; ++c2)
      // fragment (nf = wave*3+c2, kf = ks): contiguous lane-packed
      bp[c2] = *reinterpret_cast<const bf16x8*>(
          &W2t[(size_t)((wave * 3 + c2) * 24 + ks) * 512 + lane * 8]);
    #pragma unroll
    for (int r2 = 0; r2 < 2; ++r2)
      #pragma unroll
      for (int c2 = 0; c2 < 3; ++c2)
        acc2[r2][c2] = __builtin_amdgcn_mfma_f32_16x16x32_bf16(
            ap[r2], bp[c2], acc2[r2][c2], 0, 0, 0);
  }
  // ---- epilogue: + b2 + residual, write fp32 + bf16
  #pragma unroll
  for (int r2 = 0; r2 < 2; ++r2)
    #pragma unroll
    for (int c2 = 0; c2 < 3; ++c2) {
      int col = ob + c2 * 16 + lm;
      float bb2 = b2[col];
      #pragma unroll
      for (int g = 0; g < 4; ++g) {
        int row = rowBase + r2 * 16 + quad * 4 + g;
        size_t idx = (size_t)row * 192 + col;
        float v = acc2[r2][c2][g] + bb2 + resF[idx];
        Cf[idx] = v;
        Cb[idx] = f2us(v);
      }
    }
}

// ---------- MFMA GEMM 128x64: BM=128 BN=64 BK=32, 4 waves (2x2) ----------
// Depth-2 pipelined: raw s_barrier, counted vmcnt(3) steady state.
template<int ACT, int RES, int OUTF, int OUTB, int BIAS>
__global__ __launch_bounds__(256)
void mgemm(const ushort* __restrict__ A, const ushort* __restrict__ Bt,
           const float* __restrict__ bias, const float* __restrict__ resF,
           float* __restrict__ Cf, ushort* __restrict__ Cb,
           int M, int N, int K)
{
  __shared__ __align__(16) ushort Asm[2][128 * 32];
  __shared__ __align__(16) ushort Bsm[2][64 * 32];
  const int tid = threadIdx.x;
  const int wave = tid >> 6, lane = tid & 63;
  const int quad = lane >> 4, lm = lane & 15;
  const int rowBase = blockIdx.y * 128, colBase = blockIdx.x * 64;
  const int wrow = (wave & 1) * 64, wcol = (wave >> 1) * 32;
  const int srow = lane >> 2, skcol = (lane & 3) * 8;
  const int nIter = K >> 5;

  auto stage = [&](int buf, int it) {
    const int k0 = it * 32;
    #pragma unroll
    for (int uu = 0; uu < 3; ++uu) {
      const int u = wave * 3 + uu;
      if (u < 8) {
        const ushort* gp = A + (size_t)(rowBase + u * 16 + srow) * K + k0 + skcol;
        gload16(gp, &Asm[buf][u * 512]);
      } else {
        const int v = u - 8;
        const ushort* gp = Bt + (size_t)(colBase + v * 16 + srow) * K + k0 + skcol;
        gload16(gp, &Bsm[buf][v * 512]);
      }
    }
  };

  f32x4 acc[4][2] = {};
  stage(0, 0);
  if (nIter > 1) stage(1, 1);

  for (int t = 0; t < nIter; ++t) {
    const int cur = t & 1;
    if (t + 1 < nIter) asm volatile("s_waitcnt vmcnt(3)" ::: "memory");
    else               asm volatile("s_waitcnt vmcnt(0)" ::: "memory");
    __builtin_amdgcn_s_barrier();
    bf16x8 af[4], bfr[2];
    #pragma unroll
    for (int r2 = 0; r2 < 4; ++r2)
      af[r2] = *reinterpret_cast<const bf16x8*>(&Asm[cur][(wrow + r2 * 16 + lm) * 32 + quad * 8]);
    #pragma unroll
    for (int c2 = 0; c2 < 2; ++c2)
      bfr[c2] = *reinterpret_cast<const bf16x8*>(&Bsm[cur][(wcol + c2 * 16 + lm) * 32 + quad * 8]);
    asm volatile("s_waitcnt lgkmcnt(0)" ::: "memory");
    __builtin_amdgcn_s_barrier();
    if (t + 2 < nIter) stage(cur, t + 2);
    #pragma unroll
    for (int r2 = 0; r2 < 4; ++r2)
      #pragma unroll
      for (int c2 = 0; c2 < 2; ++c2)
        acc[r2][c2] = __builtin_amdgcn_mfma_f32_16x16x32_bf16(af[r2], bfr[c2], acc[r2][c2], 0, 0, 0);
  }

  #pragma unroll
  for (int r2 = 0; r2 < 4; ++r2) {
    #pragma unroll
    for (int c2 = 0; c2 < 2; ++c2) {
      int col = colBase + wcol + c2 * 16 + lm;
      int row0 = rowBase + wrow + r2 * 16 + quad * 4;
      #pragma unroll
      for (int g = 0; g < 4; ++g) {
        float v = acc[r2][c2][g];
        size_t idx = (size_t)(row0 + g) * N + col;
        if (BIAS) v += bias[col];
        if (ACT == 1) v = gelu_exact(v);
        if (RES) v += resF[idx];
        if (OUTF) Cf[idx] = v;
        if (OUTB) Cb[idx] = f2us(v);
      }
    }
  }
}

// ---------- MFMA GEMM 128x128: BM=128 BN=128 BK=32, 4 waves each 64x64 ----------
template<int ACT, int RES, int OUTF, int OUTB, int BIAS, int SPLITK>
__global__ __launch_bounds__(256)
void mgemm128(const ushort* __restrict__ A, const ushort* __restrict__ Bt,
              const float* __restrict__ bias, const float* __restrict__ resF,
              float* __restrict__ Cf, ushort* __restrict__ Cb,
              int M, int N, int K, int kChunk)
{
  __shared__ __align__(16) ushort Asm[2][128 * 32];
  __shared__ __align__(16) ushort Bsm[2][128 * 32];
  const int tid = threadIdx.x;
  const int wave = tid >> 6, lane = tid & 63;
  const int quad = lane >> 4, lm = lane & 15;
  const int rowBase = blockIdx.y * 128, colBase = blockIdx.x * 128;
  const int wrow = (wave & 1) * 64, wcol = (wave >> 1) * 64;
  const int srow = lane >> 2, skcol = (lane & 3) * 8;

  const int kbeg = SPLITK ? blockIdx.z * kChunk : 0;
  const int nIter = (SPLITK ? kChunk : K) >> 5;

  auto stage = [&](int buf, int it) {
    const int k0 = kbeg + it * 32;
    #pragma unroll
    for (int uu = 0; uu < 4; ++uu) {
      const int u = wave * 4 + uu;
      if (u < 8) {
        const ushort* gp = A + (size_t)(rowBase + u * 16 + srow) * K + k0 + skcol;
        gload16(gp, &Asm[buf][u * 512]);
      } else {
        const int v = u - 8;
        const ushort* gp = Bt + (size_t)(colBase + v * 16 + srow) * K + k0 + skcol;
        gload16(gp, &Bsm[buf][v * 512]);
      }
    }
  };

  f32x4 acc[4][4] = {};
  stage(0, 0);
  if (nIter > 1) stage(1, 1);

  for (int t = 0; t < nIter; ++t) {
    const int cur = t & 1;
    if (t + 1 < nIter) asm volatile("s_waitcnt vmcnt(4)" ::: "memory");
    else               asm volatile("s_waitcnt vmcnt(0)" ::: "memory");
    __builtin_amdgcn_s_barrier();
    bf16x8 af[4], bfr[4];
    #pragma unroll
    for (int r2 = 0; r2 < 4; ++r2)
      af[r2] = *reinterpret_cast<const bf16x8*>(&Asm[cur][(wrow + r2 * 16 + lm) * 32 + quad * 8]);
    #pragma unroll
    for (int c2 = 0; c2 < 4; ++c2)
      bfr[c2] = *reinterpret_cast<const bf16x8*>(&Bsm[cur][(wcol + c2 * 16 + lm) * 32 + quad * 8]);
    asm volatile("s_waitcnt lgkmcnt(0)" ::: "memory");
    __builtin_amdgcn_s_barrier();
    if (t + 2 < nIter) stage(cur, t + 2);
    #pragma unroll
    for (int r2 = 0; r2 < 4; ++r2)
      #pragma unroll
      for (int c2 = 0; c2 < 4; ++c2)
        acc[r2][c2] = __builtin_amdgcn_mfma_f32_16x16x32_bf16(af[r2], bfr[c2], acc[r2][c2], 0, 0, 0);
  }

  const size_t zoff = SPLITK ? (size_t)blockIdx.z * M * N : 0;
  #pragma unroll
  for (int r2 = 0; r2 < 4; ++r2) {
    #pragma unroll
    for (int c2 = 0; c2 < 4; ++c2) {
      int col = colBase + wcol + c2 * 16 + lm;
      int row0 = rowBase + wrow + r2 * 16 + quad * 4;
      #pragma unroll
      for (int g = 0; g < 4; ++g) {
        float v = acc[r2][c2][g];
        size_t idx = (size_t)(row0 + g) * N + col;
        if (BIAS) v += bias[col];
        if (ACT == 1) v = gelu_exact(v);
        if (RES) v += resF[idx];
        if (OUTF) Cf[zoff + idx] = v;
        if (OUTB) Cb[idx] = f2us(v);
      }
    }
  }
}

// ---------- split-K reduce for zg: ZG = sum_8 P + bias ----------
__global__ __launch_bounds__(256)
void reduce8_kernel(const float* __restrict__ P, const float* __restrict__ db,
                    float* __restrict__ ZG)
{
  int i = blockIdx.x * 256 + threadIdx.x;
  float s = db[i % 768];
  #pragma unroll
  for (int k = 0; k < 8; ++k) s += P[i + k * 786432];
  ZG[i] = s;
}

// ---------- split-K reduce for global fc2: out = sum_4 P + bias + res ----------
__global__ __launch_bounds__(256)
void reduce4res_kernel(const float* __restrict__ P, const float* __restrict__ db,
                       const float* __restrict__ res, float* __restrict__ out)
{
  int i = blockIdx.x * 256 + threadIdx.x;   // 3072*768
  float s = db[i % 768] + res[i];
  #pragma unroll
  for (int k = 0; k < 4; ++k) s += P[i + k * 2359296];
  out[i] = s;
}

// ---------- MFMA fused attention: one block per (seq, head), causal ----------
template<int L, int HD, int NW>
__global__ __launch_bounds__(NW * 64)
void fattn(const ushort* __restrict__ QKV, ushort* __restrict__ Yp,
           int nh, int DS, int DY, int offQ, int offK, int offV)
{
  constexpr int PQ = HD + 8;
  constexpr int PV = L + 8;
  constexpr int KS = HD / 32;
  constexpr int NCT = L / 16;
  constexpr int KS2 = L / 32;
  constexpr int NYT = HD / 16;
  constexpr int T = NW * 64;
  __shared__ __align__(16) ushort Ql[L * PQ];
  __shared__ __align__(16) ushort Kl[L * PQ];
  __shared__ __align__(16) ushort Vt[HD * PV];
  __shared__ __align__(16) ushort Ps[L * PV];
  const int tid = threadIdx.x;
  const int b = blockIdx.x / nh, h = blockIdx.x % nh;
  const size_t rowb = (size_t)b * L * DS;
  const int hb = h * HD;
  constexpr int CH = L * HD / 8;
  for (int idx = tid; idx < CH; idx += T) {
    int row = idx / (HD / 8), seg = idx % (HD / 8);
    uint4 q4 = *reinterpret_cast<const uint4*>(&QKV[rowb + (size_t)row * DS + offQ + hb + seg * 8]);
    *reinterpret_cast<uint4*>(&Ql[row * PQ + seg * 8]) = q4;
    uint4 k4 = *reinterpret_cast<const uint4*>(&QKV[rowb + (size_t)row * DS + offK + hb + seg * 8]);
    *reinterpret_cast<uint4*>(&Kl[row * PQ + seg * 8]) = k4;
  }
  for (int idx = tid; idx < L * HD; idx += T) {
    int j = idx / HD, d = idx % HD;
    Vt[d * PV + j] = QKV[rowb + (size_t)j * DS + offV + hb + d];
  }
  __syncthreads();
  const int lane = tid & 63;
  const int quad = lane >> 4, lm = lane & 15;
  const int rt = tid >> 6;
  const float scale = rsqrtf((float)HD);
  bf16x8 af[KS];
  #pragma unroll
  for (int s = 0; s < KS; ++s)
    af[s] = *reinterpret_cast<const bf16x8*>(&Ql[(rt * 16 + lm) * PQ + s * 32 + quad * 8]);
  f32x4 sacc[NCT] = {};
  #pragma unroll
  for (int ct = 0; ct < NCT; ++ct)
    #pragma unroll
    for (int s = 0; s < KS; ++s) {
      bf16x8 bf = *reinterpret_cast<const bf16x8*>(&Kl[(ct * 16 + lm) * PQ + s * 32 + quad * 8]);
      sacc[ct] = __builtin_amdgcn_mfma_f32_16x16x32_bf16(af[s], bf, sacc[ct], 0, 0, 0);
    }
  float inv[4];
  #pragma unroll
  for (int g = 0; g < 4; ++g) {
    const int row = rt * 16 + quad * 4 + g;
    float sv[NCT]; float m = -1e30f;
    #pragma unroll
    for (int ct = 0; ct < NCT; ++ct) {
      int col = ct * 16 + lm;
      float x = sacc[ct][g] * scale;
      sv[ct] = (col <= row) ? x : -1e30f;
      m = fmaxf(m, sv[ct]);
    }
    #pragma unroll
    for (int off = 8; off >= 1; off >>= 1) m = fmaxf(m, __shfl_xor(m, off));
    float l = 0.f;
    #pragma unroll
    for (int ct = 0; ct < NCT; ++ct) {
      float p = __expf(sv[ct] - m);
      l += p;
      Ps[row * PV + ct * 16 + lm] = f2us(p);
    }
    #pragma unroll
    for (int off = 8; off >= 1; off >>= 1) l += __shfl_xor(l, off);
    inv[g] = 1.f / l;
  }
  __syncthreads();
  f32x4 yacc[NYT] = {};
  #pragma unroll
  for (int s = 0; s < KS2; ++s) {
    bf16x8 ap = *reinterpret_cast<const bf16x8*>(&Ps[(rt * 16 + lm) * PV + s * 32 + quad * 8]);
    #pragma unroll
    for (int ct = 0; ct < NYT; ++ct) {
      bf16x8 bv = *reinterpret_cast<const bf16x8*>(&Vt[(ct * 16 + lm) * PV + s * 32 + quad * 8]);
      yacc[ct] = __builtin_amdgcn_mfma_f32_16x16x32_bf16(ap, bv, yacc[ct], 0, 0, 0);
    }
  }
  #pragma unroll
  for (int ct = 0; ct < NYT; ++ct)
    #pragma unroll
    for (int g = 0; g < 4; ++g) {
      int row = rt * 16 + quad * 4 + g;
      int d = ct * 16 + lm;
      Yp[((size_t)b * L + row) * DY + hb + d] = f2us(yacc[ct][g] * inv[g]);
    }
}

// ---------- zg interleave (fp32) ----------
__global__ __launch_bounds__(256)
void interleave_kernel(const float* __restrict__ zg, const float* __restrict__ xg,
                       float* __restrict__ z)
{
  int idx = blockIdx.x * 256 + threadIdx.x;
  int c = idx % 768;
  int tok = idx / 768;
  int b = tok / 96, r = tok % 96;
  int n = r / 3, t = r % 3;
  z[idx] = (t == 0) ? zg[((size_t)b * 32 + n) * 768 + c]
                    : xg[((size_t)b * 64 + 2 * n + (t - 1)) * 768 + c];
}

// ---------- final gather (fp32) ----------
__global__ __launch_bounds__(256)
void gather_kernel(const float* __restrict__ zfin, float* __restrict__ dst)
{
  int idx = blockIdx.x * 256 + threadIdx.x;
  int c = idx % 768;
  int t = (idx / 768) % 64;
  int b = idx / (768 * 64);
  int n = t >> 1, s = t & 1;
  dst[idx] = zfin[((size_t)b * 96 + 3 * n + 1 + s) * 768 + c];
}

extern "C" void kernel_launch(void* const* d_in, const int* in_sizes, int n_in,
                              void* d_out, int out_size, void* d_ws, size_t ws_size,
                              hipStream_t stream) {
  const float* xl = (const float*)d_in[0];
  const float* xg = (const float*)d_in[1];
  const float* l_ln1_w = (const float*)d_in[2];  const float* l_ln1_b = (const float*)d_in[3];
  const float* l_ln2_w = (const float*)d_in[4];  const float* l_ln2_b = (const float*)d_in[5];
  const float* l_wq = (const float*)d_in[6];     const float* l_bq = (const float*)d_in[7];
  const float* l_wk = (const float*)d_in[8];     const float* l_bk = (const float*)d_in[9];
  const float* l_wv = (const float*)d_in[10];    const float* l_bv = (const float*)d_in[11];
  const float* l_wo = (const float*)d_in[12];    const float* l_bo = (const float*)d_in[13];
  const float* l_w1 = (const float*)d_in[14];    const float* l_b1 = (const float*)d_in[15];
  const float* l_w2 = (const float*)d_in[16];    const float* l_b2 = (const float*)d_in[17];
  const float* g_ln1_w = (const float*)d_in[18]; const float* g_ln1_b = (const float*)d_in[19];
  const float* g_ln2_w = (const float*)d_in[20]; const float* g_ln2_b = (const float*)d_in[21];
  const float* g_wq = (const float*)d_in[22];    const float* g_bq = (const float*)d_in[23];
  const float* g_wk = (const float*)d_in[24];    const float* g_bk = (const float*)d_in[25];
  const float* g_wv = (const float*)d_in[26];    const float* g_bv = (const float*)d_in[27];
  const float* g_wo = (const float*)d_in[28];    const float* g_bo = (const float*)d_in[29];
  const float* g_w1 = (const float*)d_in[30];    const float* g_b1 = (const float*)d_in[31];
  const float* g_w2 = (const float*)d_in[32];    const float* g_b2 = (const float*)d_in[33];
  const float* dw   = (const float*)d_in[34];    const float* db   = (const float*)d_in[35];

  float* outL = (float*)d_out;
  float* outG = outL + 12582912;

  char* W = (char*)d_ws;
  ushort* A_bf   = (ushort*)(W + 0);
  ushort* QKVl   = (ushort*)(W + 25165824);
  ushort* XLb    = (ushort*)(W + 75497472);
  float*  X1     = (float*)(W + 100663296);
  ushort* wqkv_t = (ushort*)(W + 150994944);
  ushort* wo_t   = (ushort*)(W + 151216128);
  ushort* w1_t   = (ushort*)(W + 151289856);
  ushort* w2_t   = (ushort*)(W + 151584768);
  ushort* wd_t   = (ushort*)(W + 151879680);
  ushort* wgqkv_t= (ushort*)(W + 170754048);
  ushort* wgo_t  = (ushort*)(W + 174292992);
  ushort* wg1_t  = (ushort*)(W + 175472640);
  ushort* wg2_t  = (ushort*)(W + 180191232);
  float*  bqkv_l = (float*)(W + 184909824);
  float*  bqkv_g = (float*)(W + 184912128);
  // global-phase overlays
  float*  ZGP  = (float*)(W + 0);              // zg partials [8][1024*768]
  float*  FC2P = (float*)(W + 0);              // fc2 partials [4][3072*768] (after Z dead)
  float*  ZG   = (float*)(W + 25165824);
  float*  Z    = (float*)(W + 28311552);
  ushort* LNG  = (ushort*)(W + 37748736);
  ushort* QKVg = (ushort*)(W + 42467328);
  ushort* YG   = (ushort*)(W + 56623104);
  float*  X1G  = (float*)(W + 61341696);
  ushort* HLNG = (ushort*)(W + 70778880);
  ushort* HIDg = (ushort*)(W + 100663296);
  float*  OUTG = (float*)(W + 119537664);

  // ---- weight conversion (1 launch) + bias packs ----
  TJobs tj;
  tj.s[0] = l_wq; tj.s[1] = l_wk; tj.s[2] = l_wv; tj.s[3] = l_wo;
  tj.s[4] = l_w1; tj.s[5] = l_w2; tj.s[6] = dw;
  tj.s[7] = g_wq; tj.s[8] = g_wk; tj.s[9] = g_wv; tj.s[10] = g_wo;
  tj.s[11] = g_w1; tj.s[12] = g_w2;
  tj.d[0] = wqkv_t; tj.d[1] = wqkv_t; tj.d[2] = wqkv_t; tj.d[3] = wo_t;
  tj.d[4] = w1_t; tj.d[5] = w2_t; tj.d[6] = wd_t;
  tj.d[7] = wgqkv_t; tj.d[8] = wgqkv_t; tj.d[9] = wgqkv_t; tj.d[10] = wgo_t;
  tj.d[11] = wg1_t; tj.d[12] = wg2_t;
  transp_all<<<4140, 256, 0, stream>>>(tj);
  pack3_kernel<<<3, 256, 0, stream>>>(bqkv_l, l_bq, 192, l_bk, 192, l_bv, 192);
  pack3_kernel<<<9, 256, 0, stream>>>(bqkv_g, g_bq, 768, g_bk, 768, g_bv, 768);

  // ---- local block ----
  ln_kernel<192><<<16384, 256, 0, stream>>>(xl, l_ln1_w, l_ln1_b, A_bf, 65536);
  mgemm<0,0,0,1,1><<<dim3(9,512), 256, 0, stream>>>(A_bf, wqkv_t, bqkv_l, nullptr, nullptr, QKVl, 65536, 576, 192);
  fattn<64,32,4><<<6144, 256, 0, stream>>>(QKVl, A_bf, 6, 576, 192, 0, 192, 384);
  mgemm<0,1,1,0,1><<<dim3(3,512), 256, 0, stream>>>(A_bf, wo_t, l_bo, xl, X1, nullptr, 65536, 192, 192);
  ln_kernel<192><<<16384, 256, 0, stream>>>(X1, l_ln2_w, l_ln2_b, A_bf, 65536);
  fused_mlp<<<2048, 256, 0, stream>>>(A_bf, w1_t, w2_t, l_b1, l_b2, X1, outL, XLb);
  // ---- group summary projection (128-tile, split-K=8) + interleave ----
  mgemm128<0,0,1,0,0,1><<<dim3(6,8,8), 256, 0, stream>>>(XLb, wd_t, nullptr, nullptr, ZGP, nullptr, 1024, 768, 12288, 1536);
  reduce8_kernel<<<3072, 256, 0, stream>>>(ZGP, db, ZG);
  interleave_kernel<<<9216, 256, 0, stream>>>(ZG, xg, Z);
  // ---- global block ----
  ln_kernel<768><<<768, 256, 0, stream>>>(Z, g_ln1_w, g_ln1_b, LNG, 3072);
  mgemm128<0,0,0,1,1,0><<<dim3(18,24), 256, 0, stream>>>(LNG, wgqkv_t, bqkv_g, nullptr, nullptr, QKVg, 3072, 2304, 768, 0);
  fattn<96,64,6><<<384, 384, 0, stream>>>(QKVg, YG, 12, 2304, 768, 0, 768, 1536);
  mgemm<0,1,1,0,1><<<dim3(12,24), 256, 0, stream>>>(YG, wgo_t, g_bo, Z, X1G, nullptr, 3072, 768, 768);
  ln_kernel<768><<<768, 256, 0, stream>>>(X1G, g_ln2_w, g_ln2_b, HLNG, 3072);
  mgemm128<1,0,0,1,1,0><<<dim3(24,24), 256, 0, stream>>>(HLNG, wg1_t, g_b1, nullptr, nullptr, HIDg, 3072, 3072, 768, 0);
  mgemm128<0,0,1,0,0,1><<<dim3(6,24,4), 256, 0, stream>>>(HIDg, wg2_t, nullptr, nullptr, FC2P, nullptr, 3072, 768, 3072, 768);
  reduce4res_kernel<<<9216, 256, 0, stream>>>(FC2P, g_b2, X1G, OUTG);
  gather_kernel<<<6144, 256, 0, stream>>>(OUTG, outG);
}

// Round 8
// 631.013 us; speedup vs baseline: 1.1894x; 1.0202x over previous
//
#include <hip/hip_runtime.h>
#include <hip/hip_bf16.h>

// StARformer round 11: fused_mlp v5 — split-Hs for occupancy. v4 confirmed
// the fragment-packed layout fixed load scatter (175->114 us) but the kernel
// stays latency-bound at ~7 waves/CU (49.7 KB LDS -> 2-3 blocks/CU). v5
// halves Hs (24.5 KB): A1 | bar | B1 | bar | A2 | bar | B2, -> 6 blocks/CU
// (24 waves). acc2/afr persist across barriers (unconditional defs - no
// scratch risk per r6/r7 lesson). Also: zg GEMM split-K 8->16 for 3 blocks/CU.

typedef unsigned short ushort;
typedef __bf16 bf16x8 __attribute__((ext_vector_type(8)));
typedef float f32x4 __attribute__((ext_vector_type(4)));

__device__ __forceinline__ ushort f2us(float f) {
  __hip_bfloat16 h = __float2bfloat16(f);
  return *reinterpret_cast<ushort*>(&h);
}
__device__ __forceinline__ float gelu_exact(float v) {
  return 0.5f * v * (1.f + erff(v * 0.70710678118654752f));
}
__device__ __forceinline__ void gload16(const ushort* g, ushort* l) {
  __builtin_amdgcn_global_load_lds(
      (const __attribute__((address_space(1))) void*)g,
      (__attribute__((address_space(3))) void*)l, 16, 0, 0);
}

// ---------- batched transpose+convert: 13 weight jobs in one launch ----------
// Jobs 4 (l_w1) and 5 (l_w2) are emitted FRAGMENT-PACKED for fused_mlp:
//   frag (n>>4, k>>5) stored as 512 contiguous ushorts, lane-major.
struct TJobs { const float* s[13]; ushort* d[13]; };

__global__ __launch_bounds__(256)
void transp_all(TJobs J)
{
  static constexpr int NN[13]  = {192,192,192,192,768,192,768,768,768,768,768,3072,768};
  static constexpr int SS[13]  = {192,192,192,192,192,768,12288,768,768,768,768,768,3072};
  static constexpr int RO[13]  = {0,192,384,0,0,0,0,0,768,1536,0,0,0};
  static constexpr int FR[13]  = {0,0,0,0,1,1,0,0,0,0,0,0,0};
  static constexpr int CUM[14] = {0,9,18,27,36,72,108,2412,2556,2700,2844,2988,3564,4140};
  __shared__ float t[64][65];
  int bid = blockIdx.x;
  int j = 0;
  while (bid >= CUM[j + 1]) ++j;
  int tIdx = bid - CUM[j];
  const int N = NN[j], stride = SS[j], rowOff = RO[j];
  const int nx = N >> 6;
  const int n0 = (tIdx % nx) * 64, k0 = (tIdx / nx) * 64;
  const float* W = J.s[j];
  ushort* Wt = J.d[j];
  int c = threadIdx.x & 63, r = threadIdx.x >> 6;
  #pragma unroll
  for (int i = 0; i < 16; ++i) {
    int kr = r + i * 4;
    t[kr][c] = W[(size_t)(k0 + kr) * N + n0 + c];
  }
  __syncthreads();
  if (FR[j]) {
    #pragma unroll
    for (int i = 0; i < 16; ++i) {
      int n = n0 + r + i * 4;      // dst row (rowOff=0 for frag jobs)
      int k = k0 + c;              // dst col
      size_t fi = ((size_t)(n >> 4) * (stride >> 5) + (k >> 5)) * 512
                + (((k >> 3) & 3) * 16 + (n & 15)) * 8 + (k & 7);
      Wt[fi] = f2us(t[c][r + i * 4]);
    }
  } else {
    #pragma unroll
    for (int i = 0; i < 16; ++i) {
      int nr = r + i * 4;
      Wt[(size_t)(rowOff + n0 + nr) * stride + k0 + c] = f2us(t[c][nr]);
    }
  }
}

// ---------- pack 3 bias vectors ----------
__global__ __launch_bounds__(256)
void pack3_kernel(float* dst, const float* a, int na, const float* b, int nb,
                  const float* c, int nc)
{
  int i = blockIdx.x * 256 + threadIdx.x;
  if (i >= na + nb + nc) return;
  dst[i] = (i < na) ? a[i] : (i < na + nb ? b[i - na] : c[i - na - nb]);
}

// ---------- LayerNorm: one wave per row, fp32 in, bf16 out ----------
template<int D>
__global__ __launch_bounds__(256)
void ln_kernel(const float* __restrict__ x, const float* __restrict__ g,
               const float* __restrict__ bb, ushort* __restrict__ out, int rows)
{
  int wave = threadIdx.x >> 6, lane = threadIdx.x & 63;
  int row = blockIdx.x * 4 + wave;
  if (row >= rows) return;
  const float* xr = x + (size_t)row * D;
  constexpr int E = D / 64;
  float vals[E];
  float s = 0.f;
  #pragma unroll
  for (int e = 0; e < E; ++e) { vals[e] = xr[e * 64 + lane]; s += vals[e]; }
  #pragma unroll
  for (int off = 32; off >= 1; off >>= 1) s += __shfl_xor(s, off);
  float m = s * (1.f / D);
  float s2 = 0.f;
  #pragma unroll
  for (int e = 0; e < E; ++e) { float d = vals[e] - m; s2 += d * d; }
  #pragma unroll
  for (int off = 32; off >= 1; off >>= 1) s2 += __shfl_xor(s2, off);
  float rstd = rsqrtf(s2 * (1.f / D) + 1e-5f);
  ushort* orow = out + (size_t)row * D;
  #pragma unroll
  for (int e = 0; e < E; ++e) {
    int c = e * 64 + lane;
    orow[c] = f2us((vals[e] - m) * rstd * g[c] + bb[c]);
  }
}

// ---------- fused local MLP v5: out = res + b2 + gelu(A@w1 + b1) @ w2 ----------
// 32 rows/block. Hs holds HALF the hid row-block (k-split): A1|bar|B1|bar|A2|
// bar|B2. 24.5 KB LDS -> 6 blocks/CU. Weights read from fragment-packed layout.
__global__ __launch_bounds__(256, 4)
void fused_mlp(const ushort* __restrict__ A, const ushort* __restrict__ W1t,
               const ushort* __restrict__ W2t, const float* __restrict__ b1,
               const float* __restrict__ b2, const float* __restrict__ resF,
               float* __restrict__ Cf, ushort* __restrict__ Cb)
{
  constexpr int PH = 392;                        // 384 + 8 pad (16B-aligned rows)
  __shared__ __align__(16) ushort Hs[32 * PH];   // half hid row-block, 24.5 KB
  const int tid = threadIdx.x;
  const int wave = tid >> 6, lane = tid & 63;
  const int quad = lane >> 4, lm = lane & 15;
  const int rowBase = blockIdx.x * 32;

  // A fragments in registers for the whole kernel (unconditional defs)
  bf16x8 afr[2][6];
  #pragma unroll
  for (int r2 = 0; r2 < 2; ++r2)
    #pragma unroll
    for (int kt = 0; kt < 6; ++kt)
      afr[r2][kt] = *reinterpret_cast<const bf16x8*>(
          &A[(size_t)(rowBase + r2 * 16 + lm) * 192 + kt * 32 + quad * 8]);

  f32x4 acc2[2][3] = {};
  #pragma unroll
  for (int h = 0; h < 2; ++h) {
    // ---- phase A half h: hid cols [h*384 + wave*96, +96) -> Hs
    #pragma unroll
    for (int ct = 0; ct < 6; ++ct) {
      const int lcol = wave * 96 + ct * 16 + lm;     // 0..383 local col
      const int nf = h * 24 + wave * 6 + ct;         // W1 fragment row index
      f32x4 acc1[2] = {};
      #pragma unroll
      for (int kt = 0; kt < 6; ++kt) {
        bf16x8 bfr = *reinterpret_cast<const bf16x8*>(
            &W1t[(size_t)(nf * 6 + kt) * 512 + lane * 8]);
        #pragma unroll
        for (int r2 = 0; r2 < 2; ++r2)
          acc1[r2] = __builtin_amdgcn_mfma_f32_16x16x32_bf16(
              afr[r2][kt], bfr, acc1[r2], 0, 0, 0);
      }
      float bb1 = b1[h * 384 + lcol];
      #pragma unroll
      for (int r2 = 0; r2 < 2; ++r2)
        #pragma unroll
        for (int g = 0; g < 4; ++g) {
          int row = r2 * 16 + quad * 4 + g;
          Hs[row * PH + lcol] = f2us(gelu_exact(acc1[r2][g] + bb1));
        }
    }
    __syncthreads();   // Hs half visible
    // ---- phase B half h: acc2 += hid_half @ w2_half; out-cols [wave*48, +48)
    #pragma unroll
    for (int ks = 0; ks < 12; ++ks) {
      bf16x8 ap[2], bp[3];
      #pragma unroll
      for (int r2 = 0; r2 < 2; ++r2)
        ap[r2] = *reinterpret_cast<const bf16x8*>(
            &Hs[(r2 * 16 + lm) * PH + ks * 32 + quad * 8]);
      #pragma unroll
      for (int c2 = 0; c2 < 3; ++c2)
        bp[c2] = *reinterpret_cast<const bf16x8*>(
            &W2t[(size_t)((wave * 3 + c2) * 24 + h * 12 + ks) * 512 + lane * 8]);
      #pragma unroll
      for (int r2 = 0; r2 < 2; ++r2)
        #pragma unroll
        for (int c2 = 0; c2 < 3; ++c2)
          acc2[r2][c2] = __builtin_amdgcn_mfma_f32_16x16x32_bf16(
              ap[r2], bp[c2], acc2[r2][c2], 0, 0, 0);
    }
    __syncthreads();   // Hs reads done before next half overwrites
  }
  // ---- epilogue: + b2 + residual, write fp32 + bf16
  const int ob = wave * 48;
  #pragma unroll
  for (int r2 = 0; r2 < 2; ++r2)
    #pragma unroll
    for (int c2 = 0; c2 < 3; ++c2) {
      int col = ob + c2 * 16 + lm;
      float bb2 = b2[col];
      #pragma unroll
      for (int g = 0; g < 4; ++g) {
        int row = rowBase + r2 * 16 + quad * 4 + g;
        size_t idx = (size_t)row * 192 + col;
        float v = acc2[r2][c2][g] + bb2 + resF[idx];
        Cf[idx] = v;
        Cb[idx] = f2us(v);
      }
    }
}

// ---------- MFMA GEMM 128x64: BM=128 BN=64 BK=32, 4 waves (2x2) ----------
// Depth-2 pipelined: raw s_barrier, counted vmcnt(3) steady state.
template<int ACT, int RES, int OUTF, int OUTB, int BIAS>
__global__ __launch_bounds__(256)
void mgemm(const ushort* __restrict__ A, const ushort* __restrict__ Bt,
           const float* __restrict__ bias, const float* __restrict__ resF,
           float* __restrict__ Cf, ushort* __restrict__ Cb,
           int M, int N, int K)
{
  __shared__ __align__(16) ushort Asm[2][128 * 32];
  __shared__ __align__(16) ushort Bsm[2][64 * 32];
  const int tid = threadIdx.x;
  const int wave = tid >> 6, lane = tid & 63;
  const int quad = lane >> 4, lm = lane & 15;
  const int rowBase = blockIdx.y * 128, colBase = blockIdx.x * 64;
  const int wrow = (wave & 1) * 64, wcol = (wave >> 1) * 32;
  const int srow = lane >> 2, skcol = (lane & 3) * 8;
  const int nIter = K >> 5;

  auto stage = [&](int buf, int it) {
    const int k0 = it * 32;
    #pragma unroll
    for (int uu = 0; uu < 3; ++uu) {
      const int u = wave * 3 + uu;
      if (u < 8) {
        const ushort* gp = A + (size_t)(rowBase + u * 16 + srow) * K + k0 + skcol;
        gload16(gp, &Asm[buf][u * 512]);
      } else {
        const int v = u - 8;
        const ushort* gp = Bt + (size_t)(colBase + v * 16 + srow) * K + k0 + skcol;
        gload16(gp, &Bsm[buf][v * 512]);
      }
    }
  };

  f32x4 acc[4][2] = {};
  stage(0, 0);
  if (nIter > 1) stage(1, 1);

  for (int t = 0; t < nIter; ++t) {
    const int cur = t & 1;
    if (t + 1 < nIter) asm volatile("s_waitcnt vmcnt(3)" ::: "memory");
    else               asm volatile("s_waitcnt vmcnt(0)" ::: "memory");
    __builtin_amdgcn_s_barrier();
    bf16x8 af[4], bfr[2];
    #pragma unroll
    for (int r2 = 0; r2 < 4; ++r2)
      af[r2] = *reinterpret_cast<const bf16x8*>(&Asm[cur][(wrow + r2 * 16 + lm) * 32 + quad * 8]);
    #pragma unroll
    for (int c2 = 0; c2 < 2; ++c2)
      bfr[c2] = *reinterpret_cast<const bf16x8*>(&Bsm[cur][(wcol + c2 * 16 + lm) * 32 + quad * 8]);
    asm volatile("s_waitcnt lgkmcnt(0)" ::: "memory");
    __builtin_amdgcn_s_barrier();
    if (t + 2 < nIter) stage(cur, t + 2);
    #pragma unroll
    for (int r2 = 0; r2 < 4; ++r2)
      #pragma unroll
      for (int c2 = 0; c2 < 2; ++c2)
        acc[r2][c2] = __builtin_amdgcn_mfma_f32_16x16x32_bf16(af[r2], bfr[c2], acc[r2][c2], 0, 0, 0);
  }

  #pragma unroll
  for (int r2 = 0; r2 < 4; ++r2) {
    #pragma unroll
    for (int c2 = 0; c2 < 2; ++c2) {
      int col = colBase + wcol + c2 * 16 + lm;
      int row0 = rowBase + wrow + r2 * 16 + quad * 4;
      #pragma unroll
      for (int g = 0; g < 4; ++g) {
        float v = acc[r2][c2][g];
        size_t idx = (size_t)(row0 + g) * N + col;
        if (BIAS) v += bias[col];
        if (ACT == 1) v = gelu_exact(v);
        if (RES) v += resF[idx];
        if (OUTF) Cf[idx] = v;
        if (OUTB) Cb[idx] = f2us(v);
      }
    }
  }
}

// ---------- MFMA GEMM 128x128: BM=128 BN=128 BK=32, 4 waves each 64x64 ----------
template<int ACT, int RES, int OUTF, int OUTB, int BIAS, int SPLITK>
__global__ __launch_bounds__(256)
void mgemm128(const ushort* __restrict__ A, const ushort* __restrict__ Bt,
              const float* __restrict__ bias, const float* __restrict__ resF,
              float* __restrict__ Cf, ushort* __restrict__ Cb,
              int M, int N, int K, int kChunk)
{
  __shared__ __align__(16) ushort Asm[2][128 * 32];
  __shared__ __align__(16) ushort Bsm[2][128 * 32];
  const int tid = threadIdx.x;
  const int wave = tid >> 6, lane = tid & 63;
  const int quad = lane >> 4, lm = lane & 15;
  const int rowBase = blockIdx.y * 128, colBase = blockIdx.x * 128;
  const int wrow = (wave & 1) * 64, wcol = (wave >> 1) * 64;
  const int srow = lane >> 2, skcol = (lane & 3) * 8;

  const int kbeg = SPLITK ? blockIdx.z * kChunk : 0;
  const int nIter = (SPLITK ? kChunk : K) >> 5;

  auto stage = [&](int buf, int it) {
    const int k0 = kbeg + it * 32;
    #pragma unroll
    for (int uu = 0; uu < 4; ++uu) {
      const int u = wave * 4 + uu;
      if (u < 8) {
        const ushort* gp = A + (size_t)(rowBase + u * 16 + srow) * K + k0 + skcol;
        gload16(gp, &Asm[buf][u * 512]);
      } else {
        const int v = u - 8;
        const ushort* gp = Bt + (size_t)(colBase + v * 16 + srow) * K + k0 + skcol;
        gload16(gp, &Bsm[buf][v * 512]);
      }
    }
  };

  f32x4 acc[4][4] = {};
  stage(0, 0);
  if (nIter > 1) stage(1, 1);

  for (int t = 0; t < nIter; ++t) {
    const int cur = t & 1;
    if (t + 1 < nIter) asm volatile("s_waitcnt vmcnt(4)" ::: "memory");
    else               asm volatile("s_waitcnt vmcnt(0)" ::: "memory");
    __builtin_amdgcn_s_barrier();
    bf16x8 af[4], bfr[4];
    #pragma unroll
    for (int r2 = 0; r2 < 4; ++r2)
      af[r2] = *reinterpret_cast<const bf16x8*>(&Asm[cur][(wrow + r2 * 16 + lm) * 32 + quad * 8]);
    #pragma unroll
    for (int c2 = 0; c2 < 4; ++c2)
      bfr[c2] = *reinterpret_cast<const bf16x8*>(&Bsm[cur][(wcol + c2 * 16 + lm) * 32 + quad * 8]);
    asm volatile("s_waitcnt lgkmcnt(0)" ::: "memory");
    __builtin_amdgcn_s_barrier();
    if (t + 2 < nIter) stage(cur, t + 2);
    #pragma unroll
    for (int r2 = 0; r2 < 4; ++r2)
      #pragma unroll
      for (int c2 = 0; c2 < 4; ++c2)
        acc[r2][c2] = __builtin_amdgcn_mfma_f32_16x16x32_bf16(af[r2], bfr[c2], acc[r2][c2], 0, 0, 0);
  }

  const size_t zoff = SPLITK ? (size_t)blockIdx.z * M * N : 0;
  #pragma unroll
  for (int r2 = 0; r2 < 4; ++r2) {
    #pragma unroll
    for (int c2 = 0; c2 < 4; ++c2) {
      int col = colBase + wcol + c2 * 16 + lm;
      int row0 = rowBase + wrow + r2 * 16 + quad * 4;
      #pragma unroll
      for (int g = 0; g < 4; ++g) {
        float v = acc[r2][c2][g];
        size_t idx = (size_t)(row0 + g) * N + col;
        if (BIAS) v += bias[col];
        if (ACT == 1) v = gelu_exact(v);
        if (RES) v += resF[idx];
        if (OUTF) Cf[zoff + idx] = v;
        if (OUTB) Cb[idx] = f2us(v);
      }
    }
  }
}

// ---------- split-K reduce for zg: ZG = sum_16 P + bias ----------
__global__ __launch_bounds__(256)
void reduce16_kernel(const float* __restrict__ P, const float* __restrict__ db,
                     float* __restrict__ ZG)
{
  int i = blockIdx.x * 256 + threadIdx.x;
  float s = db[i % 768];
  #pragma unroll
  for (int k = 0; k < 16; ++k) s += P[i + k * 786432];
  ZG[i] = s;
}

// ---------- split-K reduce for global fc2: out = sum_4 P + bias + res ----------
__global__ __launch_bounds__(256)
void reduce4res_kernel(const float* __restrict__ P, const float* __restrict__ db,
                       const float* __restrict__ res, float* __restrict__ out)
{
  int i = blockIdx.x * 256 + threadIdx.x;   // 3072*768
  float s = db[i % 768] + res[i];
  #pragma unroll
  for (int k = 0; k < 4; ++k) s += P[i + k * 2359296];
  out[i] = s;
}

// ---------- MFMA fused attention: one block per (seq, head), causal ----------
template<int L, int HD, int NW>
__global__ __launch_bounds__(NW * 64)
void fattn(const ushort* __restrict__ QKV, ushort* __restrict__ Yp,
           int nh, int DS, int DY, int offQ, int offK, int offV)
{
  constexpr int PQ = HD + 8;
  constexpr int PV = L + 8;
  constexpr int KS = HD / 32;
  constexpr int NCT = L / 16;
  constexpr int KS2 = L / 32;
  constexpr int NYT = HD / 16;
  constexpr int T = NW * 64;
  __shared__ __align__(16) ushort Ql[L * PQ];
  __shared__ __align__(16) ushort Kl[L * PQ];
  __shared__ __align__(16) ushort Vt[HD * PV];
  __shared__ __align__(16) ushort Ps[L * PV];
  const int tid = threadIdx.x;
  const int b = blockIdx.x / nh, h = blockIdx.x % nh;
  const size_t rowb = (size_t)b * L * DS;
  const int hb = h * HD;
  constexpr int CH = L * HD / 8;
  for (int idx = tid; idx < CH; idx += T) {
    int row = idx / (HD / 8), seg = idx % (HD / 8);
    uint4 q4 = *reinterpret_cast<const uint4*>(&QKV[rowb + (size_t)row * DS + offQ + hb + seg * 8]);
    *reinterpret_cast<uint4*>(&Ql[row * PQ + seg * 8]) = q4;
    uint4 k4 = *reinterpret_cast<const uint4*>(&QKV[rowb + (size_t)row * DS + offK + hb + seg * 8]);
    *reinterpret_cast<uint4*>(&Kl[row * PQ + seg * 8]) = k4;
  }
  for (int idx = tid; idx < L * HD; idx += T) {
    int j = idx / HD, d = idx % HD;
    Vt[d * PV + j] = QKV[rowb + (size_t)j * DS + offV + hb + d];
  }
  __syncthreads();
  const int lane = tid & 63;
  const int quad = lane >> 4, lm = lane & 15;
  const int rt = tid >> 6;
  const float scale = rsqrtf((float)HD);
  bf16x8 af[KS];
  #pragma unroll
  for (int s = 0; s < KS; ++s)
    af[s] = *reinterpret_cast<const bf16x8*>(&Ql[(rt * 16 + lm) * PQ + s * 32 + quad * 8]);
  f32x4 sacc[NCT] = {};
  #pragma unroll
  for (int ct = 0; ct < NCT; ++ct)
    #pragma unroll
    for (int s = 0; s < KS; ++s) {
      bf16x8 bf = *reinterpret_cast<const bf16x8*>(&Kl[(ct * 16 + lm) * PQ + s * 32 + quad * 8]);
      sacc[ct] = __builtin_amdgcn_mfma_f32_16x16x32_bf16(af[s], bf, sacc[ct], 0, 0, 0);
    }
  float inv[4];
  #pragma unroll
  for (int g = 0; g < 4; ++g) {
    const int row = rt * 16 + quad * 4 + g;
    float sv[NCT]; float m = -1e30f;
    #pragma unroll
    for (int ct = 0; ct < NCT; ++ct) {
      int col = ct * 16 + lm;
      float x = sacc[ct][g] * scale;
      sv[ct] = (col <= row) ? x : -1e30f;
      m = fmaxf(m, sv[ct]);
    }
    #pragma unroll
    for (int off = 8; off >= 1; off >>= 1) m = fmaxf(m, __shfl_xor(m, off));
    float l = 0.f;
    #pragma unroll
    for (int ct = 0; ct < NCT; ++ct) {
      float p = __expf(sv[ct] - m);
      l += p;
      Ps[row * PV + ct * 16 + lm] = f2us(p);
    }
    #pragma unroll
    for (int off = 8; off >= 1; off >>= 1) l += __shfl_xor(l, off);
    inv[g] = 1.f / l;
  }
  __syncthreads();
  f32x4 yacc[NYT] = {};
  #pragma unroll
  for (int s = 0; s < KS2; ++s) {
    bf16x8 ap = *reinterpret_cast<const bf16x8*>(&Ps[(rt * 16 + lm) * PV + s * 32 + quad * 8]);
    #pragma unroll
    for (int ct = 0; ct < NYT; ++ct) {
      bf16x8 bv = *reinterpret_cast<const bf16x8*>(&Vt[(ct * 16 + lm) * PV + s * 32 + quad * 8]);
      yacc[ct] = __builtin_amdgcn_mfma_f32_16x16x32_bf16(ap, bv, yacc[ct], 0, 0, 0);
    }
  }
  #pragma unroll
  for (int ct = 0; ct < NYT; ++ct)
    #pragma unroll
    for (int g = 0; g < 4; ++g) {
      int row = rt * 16 + quad * 4 + g;
      int d = ct * 16 + lm;
      Yp[((size_t)b * L + row) * DY + hb + d] = f2us(yacc[ct][g] * inv[g]);
    }
}

// ---------- zg interleave (fp32) ----------
__global__ __launch_bounds__(256)
void interleave_kernel(const float* __restrict__ zg, const float* __restrict__ xg,
                       float* __restrict__ z)
{
  int idx = blockIdx.x * 256 + threadIdx.x;
  int c = idx % 768;
  int tok = idx / 768;
  int b = tok / 96, r = tok % 96;
  int n = r / 3, t = r % 3;
  z[idx] = (t == 0) ? zg[((size_t)b * 32 + n) * 768 + c]
                    : xg[((size_t)b * 64 + 2 * n + (t - 1)) * 768 + c];
}

// ---------- final gather (fp32) ----------
__global__ __launch_bounds__(256)
void gather_kernel(const float* __restrict__ zfin, float* __restrict__ dst)
{
  int idx = blockIdx.x * 256 + threadIdx.x;
  int c = idx % 768;
  int t = (idx / 768) % 64;
  int b = idx / (768 * 64);
  int n = t >> 1, s = t & 1;
  dst[idx] = zfin[((size_t)b * 96 + 3 * n + 1 + s) * 768 + c];
}

extern "C" void kernel_launch(void* const* d_in, const int* in_sizes, int n_in,
                              void* d_out, int out_size, void* d_ws, size_t ws_size,
                              hipStream_t stream) {
  const float* xl = (const float*)d_in[0];
  const float* xg = (const float*)d_in[1];
  const float* l_ln1_w = (const float*)d_in[2];  const float* l_ln1_b = (const float*)d_in[3];
  const float* l_ln2_w = (const float*)d_in[4];  const float* l_ln2_b = (const float*)d_in[5];
  const float* l_wq = (const float*)d_in[6];     const float* l_bq = (const float*)d_in[7];
  const float* l_wk = (const float*)d_in[8];     const float* l_bk = (const float*)d_in[9];
  const float* l_wv = (const float*)d_in[10];    const float* l_bv = (const float*)d_in[11];
  const float* l_wo = (const float*)d_in[12];    const float* l_bo = (const float*)d_in[13];
  const float* l_w1 = (const float*)d_in[14];    const float* l_b1 = (const float*)d_in[15];
  const float* l_w2 = (const float*)d_in[16];    const float* l_b2 = (const float*)d_in[17];
  const float* g_ln1_w = (const float*)d_in[18]; const float* g_ln1_b = (const float*)d_in[19];
  const float* g_ln2_w = (const float*)d_in[20]; const float* g_ln2_b = (const float*)d_in[21];
  const float* g_wq = (const float*)d_in[22];    const float* g_bq = (const float*)d_in[23];
  const float* g_wk = (const float*)d_in[24];    const float* g_bk = (const float*)d_in[25];
  const float* g_wv = (const float*)d_in[26];    const float* g_bv = (const float*)d_in[27];
  const float* g_wo = (const float*)d_in[28];    const float* g_bo = (const float*)d_in[29];
  const float* g_w1 = (const float*)d_in[30];    const float* g_b1 = (const float*)d_in[31];
  const float* g_w2 = (const float*)d_in[32];    const float* g_b2 = (const float*)d_in[33];
  const float* dw   = (const float*)d_in[34];    const float* db   = (const float*)d_in[35];

  float* outL = (float*)d_out;
  float* outG = outL + 12582912;

  char* W = (char*)d_ws;
  ushort* A_bf   = (ushort*)(W + 0);
  ushort* QKVl   = (ushort*)(W + 25165824);
  ushort* XLb    = (ushort*)(W + 75497472);
  float*  X1     = (float*)(W + 100663296);
  ushort* wqkv_t = (ushort*)(W + 150994944);
  ushort* wo_t   = (ushort*)(W + 151216128);
  ushort* w1_t   = (ushort*)(W + 151289856);
  ushort* w2_t   = (ushort*)(W + 151584768);
  ushort* wd_t   = (ushort*)(W + 151879680);
  ushort* wgqkv_t= (ushort*)(W + 170754048);
  ushort* wgo_t  = (ushort*)(W + 174292992);
  ushort* wg1_t  = (ushort*)(W + 175472640);
  ushort* wg2_t  = (ushort*)(W + 180191232);
  float*  bqkv_l = (float*)(W + 184909824);
  float*  bqkv_g = (float*)(W + 184912128);
  // global-phase overlays
  float*  ZGP  = (float*)(W + 0);              // zg partials [16][1024*768] = 50.3 MB
  float*  FC2P = (float*)(W + 0);              // fc2 partials [4][3072*768] (after Z dead)
  float*  ZG   = (float*)(W + 130023424);      // 3.1 MB (moved clear of bigger ZGP)
  float*  Z    = (float*)(W + 28311552);
  ushort* LNG  = (ushort*)(W + 37748736);
  ushort* QKVg = (ushort*)(W + 42467328);
  ushort* YG   = (ushort*)(W + 56623104);
  float*  X1G  = (float*)(W + 61341696);
  ushort* HLNG = (ushort*)(W + 70778880);
  ushort* HIDg = (ushort*)(W + 100663296);
  float*  OUTG = (float*)(W + 119537664);

  // ---- weight conversion (1 launch) + bias packs ----
  TJobs tj;
  tj.s[0] = l_wq; tj.s[1] = l_wk; tj.s[2] = l_wv; tj.s[3] = l_wo;
  tj.s[4] = l_w1; tj.s[5] = l_w2; tj.s[6] = dw;
  tj.s[7] = g_wq; tj.s[8] = g_wk; tj.s[9] = g_wv; tj.s[10] = g_wo;
  tj.s[11] = g_w1; tj.s[12] = g_w2;
  tj.d[0] = wqkv_t; tj.d[1] = wqkv_t; tj.d[2] = wqkv_t; tj.d[3] = wo_t;
  tj.d[4] = w1_t; tj.d[5] = w2_t; tj.d[6] = wd_t;
  tj.d[7] = wgqkv_t; tj.d[8] = wgqkv_t; tj.d[9] = wgqkv_t; tj.d[10] = wgo_t;
  tj.d[11] = wg1_t; tj.d[12] = wg2_t;
  transp_all<<<4140, 256, 0, stream>>>(tj);
  pack3_kernel<<<3, 256, 0, stream>>>(bqkv_l, l_bq, 192, l_bk, 192, l_bv, 192);
  pack3_kernel<<<9, 256, 0, stream>>>(bqkv_g, g_bq, 768, g_bk, 768, g_bv, 768);

  // ---- local block ----
  ln_kernel<192><<<16384, 256, 0, stream>>>(xl, l_ln1_w, l_ln1_b, A_bf, 65536);
  mgemm<0,0,0,1,1><<<dim3(9,512), 256, 0, stream>>>(A_bf, wqkv_t, bqkv_l, nullptr, nullptr, QKVl, 65536, 576, 192);
  fattn<64,32,4><<<6144, 256, 0, stream>>>(QKVl, A_bf, 6, 576, 192, 0, 192, 384);
  mgemm<0,1,1,0,1><<<dim3(3,512), 256, 0, stream>>>(A_bf, wo_t, l_bo, xl, X1, nullptr, 65536, 192, 192);
  ln_kernel<192><<<16384, 256, 0, stream>>>(X1, l_ln2_w, l_ln2_b, A_bf, 65536);
  fused_mlp<<<2048, 256, 0, stream>>>(A_bf, w1_t, w2_t, l_b1, l_b2, X1, outL, XLb);
  // ---- group summary projection (128-tile, split-K=16) + interleave ----
  mgemm128<0,0,1,0,0,1><<<dim3(6,8,16), 256, 0, stream>>>(XLb, wd_t, nullptr, nullptr, ZGP, nullptr, 1024, 768, 12288, 768);
  reduce16_kernel<<<3072, 256, 0, stream>>>(ZGP, db, ZG);
  interleave_kernel<<<9216, 256, 0, stream>>>(ZG, xg, Z);
  // ---- global block ----
  ln_kernel<768><<<768, 256, 0, stream>>>(Z, g_ln1_w, g_ln1_b, LNG, 3072);
  mgemm128<0,0,0,1,1,0><<<dim3(18,24), 256, 0, stream>>>(LNG, wgqkv_t, bqkv_g, nullptr, nullptr, QKVg, 3072, 2304, 768, 0);
  fattn<96,64,6><<<384, 384, 0, stream>>>(QKVg, YG, 12, 2304, 768, 0, 768, 1536);
  mgemm<0,1,1,0,1><<<dim3(12,24), 256, 0, stream>>>(YG, wgo_t, g_bo, Z, X1G, nullptr, 3072, 768, 768);
  ln_kernel<768><<<768, 256, 0, stream>>>(X1G, g_ln2_w, g_ln2_b, HLNG, 3072);
  mgemm128<1,0,0,1,1,0><<<dim3(24,24), 256, 0, stream>>>(HLNG, wg1_t, g_b1, nullptr, nullptr, HIDg, 3072, 3072, 768, 0);
  mgemm128<0,0,1,0,0,1><<<dim3(6,24,4), 256, 0, stream>>>(HIDg, wg2_t, nullptr, nullptr, FC2P, nullptr, 3072, 768, 3072, 768);
  reduce4res_kernel<<<9216, 256, 0, stream>>>(FC2P, g_b2, X1G, OUTG);
  gather_kernel<<<6144, 256, 0, stream>>>(OUTG, outG);
}